// Round 5
// baseline (199.119 us; speedup 1.0000x reference)
//
#include <hip/hip_runtime.h>
#include <hip/hip_bf16.h>

#define DIM 768
#define NHEADS 12
#define NTOK 197
#define NP 208         // padded tokens (13*16)
#define NPS 232        // VT / P LDS row stride in shorts
#define M_ROWS 12608   // B*N
#define M_PAD 12800    // 50*256
#define HEADS_TOT 768  // B*H
#define NT 24          // K-tiles of 32 (768/32)

typedef __attribute__((ext_vector_type(8))) short bf16x8;
typedef __attribute__((ext_vector_type(4))) float f32x4;

__device__ inline short f2bf(float f) {
  union { __hip_bfloat16 h; short s; } u;
  u.h = __float2bfloat16(f);
  return u.s;
}

__device__ __forceinline__ void gload16(const short* g, short* l) {
  __builtin_amdgcn_global_load_lds((const __attribute__((address_space(1))) void*)g,
                                   (__attribute__((address_space(3))) void*)l, 16, 0, 0);
}

// bijective XCD-aware swizzle (m204)
__device__ __forceinline__ int xcd_swz(int orig, int nwg) {
  int q = nwg >> 3, r = nwg & 7;
  int x = orig & 7, p = orig >> 3;
  return (x < r ? x * (q + 1) : r * (q + 1) + (x - r) * q) + p;
}

// ---------------- convert fp32 -> bf16 (x, qkv_weight, proj_weight) + zero xb pad rows ----------------
__global__ void convert_kernel(const float* __restrict__ x, const float* __restrict__ wq,
                               const float* __restrict__ wp,
                               short* __restrict__ xb, short* __restrict__ wqb,
                               short* __restrict__ wpb) {
  int idx = blockIdx.x * 256 + threadIdx.x;
  const int n_x  = M_ROWS * DIM / 4;
  const int n_wq = 3 * DIM * DIM / 4;
  const int n_wp = DIM * DIM / 4;
  const int n_pad = (M_PAD - M_ROWS) * DIM / 4;
  if (idx >= n_x + n_wq + n_wp) {
    int k = idx - n_x - n_wq - n_wp;
    if (k < n_pad) {
      short4 z = {0, 0, 0, 0};
      *(short4*)(xb + (size_t)M_ROWS * DIM + (size_t)k * 4) = z;
    }
    return;
  }
  const float4* src; short* dst; int off;
  if (idx < n_x)             { src = (const float4*)x;  dst = xb;  off = idx; }
  else if (idx < n_x + n_wq) { src = (const float4*)wq; dst = wqb; off = idx - n_x; }
  else                       { src = (const float4*)wp; dst = wpb; off = idx - n_x - n_wq; }
  float4 v = src[off];
  short4 o;
  o.x = f2bf(v.x); o.y = f2bf(v.y); o.z = f2bf(v.z); o.w = f2bf(v.w);
  *(short4*)(dst + (size_t)off * 4) = o;
}

// ---------------- expand relative position bias to [12][208][208] fp32 ----------------
__global__ void rpb_kernel(const float* __restrict__ table, float* __restrict__ rpbf) {
  int idx = blockIdx.x * 256 + threadIdx.x;
  const int tot = NHEADS * NP * NP;
  if (idx >= tot) return;
  int h = idx / (NP * NP);
  int rem = idx - h * NP * NP;
  int i = rem / NP;
  int j = rem - i * NP;
  float v = 0.f;
  if (i < NTOK && j < NTOK) {
    int t;
    if (i == 0 && j == 0) t = 731;
    else if (i == 0)      t = 729;
    else if (j == 0)      t = 730;
    else {
      int p = i - 1, q = j - 1;
      int ri = p / 14, ci = p - ri * 14;
      int rj = q / 14, cj = q - rj * 14;
      t = (ri - rj + 13) * 27 + (ci - cj + 13);
    }
    v = table[t * NHEADS + h];
  }
  rpbf[idx] = v;
}

// ================= 256x256 pipelined GEMM (BK=32, 4-deep ring, counted vmcnt) =================
// LDS per K-tile buffer (32KB = 16384 shorts): A [2 halves][128][4 slots of 8], B at +8192.
// Slot rotation: lds_slot = (logical_slot + row) & 3  -> 2-way (free) ds_read_b128 banks.
// Per K-tile: 4 phases = quadrant(mh,nh) x K=32, 8 MFMA each; each phase stages one
// half-tile of K-tile kt+3 (whose buffer's last reader finished before this K-tile's
// opening barrier). One vmcnt(8)+barrier per K-tile; never drain-0 mid-loop.

template<bool DOSTAGE>
__device__ __forceinline__ void ktile256(int kt, short* lds,
                                         const short* Asrc, const short* Bsrc, short* sdst,
                                         int aoff, int boff, f32x4 (&acc)[8][4]) {
  const short* Ab = lds + (kt & 3) * 16384 + aoff;
  const short* Bb = lds + (kt & 3) * 16384 + boff;
#pragma unroll
  for (int mh = 0; mh < 2; ++mh) {
    bf16x8 af[4];
#pragma unroll
    for (int nh = 0; nh < 2; ++nh) {
      if (DOSTAGE) {
        const int ph = mh * 2 + nh;   // 0:A0 1:A1 2:B0 3:B1 of ktile kt+3
        gload16((ph >= 2 ? Bsrc : Asrc) + (size_t)(ph & 1) * 128 * DIM + (kt + 3) * 32,
                sdst + ((kt + 3) & 3) * 16384 + (ph >= 2 ? 8192 : 0) + (ph & 1) * 4096);
      }
      if (nh == 0) {
#pragma unroll
        for (int j = 0; j < 4; ++j) af[j] = *(const bf16x8*)(Ab + (mh * 4 + j) * 512);
      }
      bf16x8 bfr[2];
#pragma unroll
      for (int j = 0; j < 2; ++j) bfr[j] = *(const bf16x8*)(Bb + (nh * 2 + j) * 512);
      __builtin_amdgcn_s_setprio(1);
#pragma unroll
      for (int j = 0; j < 4; ++j)
#pragma unroll
        for (int i2 = 0; i2 < 2; ++i2)
          acc[mh * 4 + j][nh * 2 + i2] = __builtin_amdgcn_mfma_f32_16x16x32_bf16(
              af[j], bfr[i2], acc[mh * 4 + j][nh * 2 + i2], 0, 0, 0);
      __builtin_amdgcn_s_setprio(0);
    }
  }
}

__device__ __forceinline__ void gemm256_mainloop(const short* __restrict__ A,
                                                 const short* __restrict__ Bw,
                                                 int tm, int tn, short* lds, f32x4 (&acc)[8][4]) {
  const int tid = threadIdx.x;
  const int w = tid >> 6, wm = w >> 2, wn = w & 3;
  const int l = tid & 63, lr = l & 15, lg = l >> 4;
  const int srow = tid >> 2;                       // staging row within half (0..127)
  const int sslot = ((tid & 3) - srow) & 3;        // pre-rotated source slot
  const short* Asrc = A + (size_t)(tm * 256 + srow) * DIM + sslot * 8;
  const short* Bsrc = Bw + (size_t)(tn * 256 + srow) * DIM + sslot * 8;
  short* sdst = lds + tid * 8;                     // linear gload_lds dest
  const int aoff = wm * 4096 + lr * 32 + (((lg + lr) & 3) << 3);
  const int boff = 8192 + (wn >> 1) * 4096 + ((wn & 1) * 64 + lr) * 32 + (((lg + lr) & 3) << 3);
#pragma unroll
  for (int m = 0; m < 8; ++m)
#pragma unroll
    for (int n = 0; n < 4; ++n) { f32x4 z = {0.f, 0.f, 0.f, 0.f}; acc[m][n] = z; }

  // prologue: stage K-tiles 0,1,2 (12 loads/thread); wait for tile 0 only
#pragma unroll
  for (int kt = 0; kt < 3; ++kt)
#pragma unroll
    for (int ph = 0; ph < 4; ++ph)
      gload16((ph >= 2 ? Bsrc : Asrc) + (size_t)(ph & 1) * 128 * DIM + kt * 32,
              sdst + (kt & 3) * 16384 + (ph >= 2 ? 8192 : 0) + (ph & 1) * 4096);
  asm volatile("s_waitcnt vmcnt(8)" ::: "memory");
  __builtin_amdgcn_s_barrier();

  for (int kt = 0; kt < NT - 3; ++kt) {
    ktile256<true>(kt, lds, Asrc, Bsrc, sdst, aoff, boff, acc);
    asm volatile("s_waitcnt vmcnt(8)" ::: "memory");   // kt+1 resident; kt+2,kt+3 in flight
    __builtin_amdgcn_s_barrier();
  }
  ktile256<false>(NT - 3, lds, Asrc, Bsrc, sdst, aoff, boff, acc);
  asm volatile("s_waitcnt vmcnt(4)" ::: "memory");
  __builtin_amdgcn_s_barrier();
  ktile256<false>(NT - 2, lds, Asrc, Bsrc, sdst, aoff, boff, acc);
  asm volatile("s_waitcnt vmcnt(0)" ::: "memory");
  __builtin_amdgcn_s_barrier();
  ktile256<false>(NT - 1, lds, Asrc, Bsrc, sdst, aoff, boff, acc);
}

// ---------------- QKV GEMM: epilogue scatters to q/k/v^T head-major buffers ----------------
__global__ __launch_bounds__(512)
void gemm_qkv_kernel(const short* __restrict__ xb, const short* __restrict__ wqb,
                     const float* __restrict__ q_bias, const float* __restrict__ v_bias,
                     short* __restrict__ qbuf, short* __restrict__ kbuf,
                     short* __restrict__ vtbuf) {
  __shared__ __attribute__((aligned(16))) short lds[65536];   // 128 KB
  const int wg = xcd_swz(blockIdx.x, 50 * 9);
  const int tn = wg % 9, tm = wg / 9;
  f32x4 acc[8][4];
  gemm256_mainloop(xb, wqb, tm, tn, lds, acc);

  const int tid = threadIdx.x;
  const int w = tid >> 6, wm = w >> 2, wn = w & 3;
  const int l = tid & 63, lr = l & 15, lg = l >> 4;
  const int rbase = tm * 256 + wm * 128, cbase = tn * 256 + wn * 64;
#pragma unroll
  for (int n = 0; n < 4; ++n) {
    int c = cbase + n * 16 + lr;
    int part = (c < 768) ? 0 : ((c < 1536) ? 1 : 2);
    int f = c - part * 768;
    int hh = f >> 6, d = f & 63;
    float bias = (part == 0) ? q_bias[c] : ((part == 2) ? v_bias[f] : 0.f);
#pragma unroll
    for (int m = 0; m < 8; ++m) {
#pragma unroll
      for (int i = 0; i < 4; ++i) {
        int r = rbase + m * 16 + lg * 4 + i;
        if (r < M_ROWS) {
          int b = r / 197, nn = r - b * 197;
          int bh = b * 12 + hh;
          float v = acc[m][n][i] + bias;
          if (part == 0)      qbuf[(size_t)(bh * NP + nn) * 64 + d] = f2bf(v * 0.125f);
          else if (part == 1) kbuf[(size_t)(bh * NP + nn) * 64 + d] = f2bf(v);
          else                vtbuf[(size_t)(bh * 64 + d) * NP + nn] = f2bf(v);
        }
      }
    }
  }
}

// ---------------- proj GEMM: fp32 out + bias ----------------
__global__ __launch_bounds__(512)
void gemm_proj_kernel(const short* __restrict__ ab, const short* __restrict__ wpb,
                      const float* __restrict__ proj_bias, float* __restrict__ out) {
  __shared__ __attribute__((aligned(16))) short lds[65536];
  const int wg = xcd_swz(blockIdx.x, 50 * 3);
  const int tn = wg % 3, tm = wg / 3;
  f32x4 acc[8][4];
  gemm256_mainloop(ab, wpb, tm, tn, lds, acc);

  const int tid = threadIdx.x;
  const int w = tid >> 6, wm = w >> 2, wn = w & 3;
  const int l = tid & 63, lr = l & 15, lg = l >> 4;
  const int rbase = tm * 256 + wm * 128, cbase = tn * 256 + wn * 64;
#pragma unroll
  for (int n = 0; n < 4; ++n) {
    int c = cbase + n * 16 + lr;
    float pb = proj_bias[c];
#pragma unroll
    for (int m = 0; m < 8; ++m) {
#pragma unroll
      for (int i = 0; i < 4; ++i) {
        int r = rbase + m * 16 + lg * 4 + i;
        if (r < M_ROWS) out[(size_t)r * DIM + c] = acc[m][n][i] + pb;
      }
    }
  }
}

// ---------------- attention: one block (8 waves) per (b,h), K/V^T LDS-resident ----------------
__global__ __launch_bounds__(512, 1)
void attn_kernel(const short* __restrict__ qbuf, const short* __restrict__ kbuf,
                 const short* __restrict__ vtbuf, const float* __restrict__ rpbf,
                 short* __restrict__ aout) {
  __shared__ __attribute__((aligned(16))) short Klds[208 * 64];
  __shared__ __attribute__((aligned(16))) short Vlds[64 * NPS];
  __shared__ __attribute__((aligned(16))) short Plds[8 * 16 * NPS];
  const int bh = blockIdx.x;
  const int b = bh / 12, h = bh - b * 12;
  const short* Qg = qbuf + (size_t)bh * NP * 64;
  const short* Kg = kbuf + (size_t)bh * NP * 64;
  const short* Vg = vtbuf + (size_t)bh * 64 * NP;
  const float* RP = rpbf + (size_t)h * NP * NP;
  const int tid = threadIdx.x;
  const int wave = tid >> 6, l = tid & 63, lr = l & 15, lg = l >> 4;

  for (int c = tid; c < 1664; c += 512) {
    int r = c >> 3, sp = c & 7;
    gload16(Kg + r * 64 + ((sp ^ (r & 7)) << 3), Klds + c * 8);
  }
  for (int c = tid; c < 64 * 29; c += 512) {
    int r = c / 29, sp = c - r * 29;
    int sg = sp < 26 ? sp : 25;
    gload16(Vg + r * NP + sg * 8, Vlds + c * 8);
  }
  __syncthreads();
  if (tid < 64) {
    for (int j = NTOK; j < NPS; ++j) Vlds[tid * NPS + j] = 0;
  }
  __syncthreads();

  short* Pw = Plds + wave * 16 * NPS;
  for (int s = wave; s < 13; s += 8) {
    const int row0 = s * 16;
    bf16x8 qf0 = *(const bf16x8*)(Qg + (row0 + lr) * 64 + lg * 8);
    bf16x8 qf1 = *(const bf16x8*)(Qg + (row0 + lr) * 64 + 32 + lg * 8);
    f32x4 acc[13];
#pragma unroll
    for (int t = 0; t < 13; ++t) { f32x4 z = {0.f, 0.f, 0.f, 0.f}; acc[t] = z; }
    __builtin_amdgcn_s_setprio(1);
#pragma unroll
    for (int t = 0; t < 13; ++t) {
      int rk = t * 16 + lr;
      int sw = lr & 7;
      bf16x8 kf0 = *(const bf16x8*)(Klds + rk * 64 + ((lg ^ sw) << 3));
      bf16x8 kf1 = *(const bf16x8*)(Klds + rk * 64 + (((4 + lg) ^ sw) << 3));
      acc[t] = __builtin_amdgcn_mfma_f32_16x16x32_bf16(qf0, kf0, acc[t], 0, 0, 0);
      acc[t] = __builtin_amdgcn_mfma_f32_16x16x32_bf16(qf1, kf1, acc[t], 0, 0, 0);
    }
    __builtin_amdgcn_s_setprio(0);
    float sum4[4];
#pragma unroll
    for (int i = 0; i < 4; ++i) {
      const int row = row0 + lg * 4 + i;
      const float* rp = RP + (size_t)row * NP;
      float sv[13];
      float mx = -3e38f;
#pragma unroll
      for (int t = 0; t < 13; ++t) {
        int col = t * 16 + lr;
        float s_ = (col < NTOK) ? (acc[t][i] + rp[col]) : -3e38f;
        sv[t] = s_;
        mx = fmaxf(mx, s_);
      }
      mx = fmaxf(mx, __shfl_xor(mx, 1, 16));
      mx = fmaxf(mx, __shfl_xor(mx, 2, 16));
      mx = fmaxf(mx, __shfl_xor(mx, 4, 16));
      mx = fmaxf(mx, __shfl_xor(mx, 8, 16));
      float sm = 0.f;
#pragma unroll
      for (int t = 0; t < 13; ++t) {
        float p = __expf(sv[t] - mx);
        sm += p;
        Pw[(lg * 4 + i) * NPS + t * 16 + lr] = f2bf(p);
      }
      sm += __shfl_xor(sm, 1, 16);
      sm += __shfl_xor(sm, 2, 16);
      sm += __shfl_xor(sm, 4, 16);
      sm += __shfl_xor(sm, 8, 16);
      sum4[i] = sm;
      Pw[(lg * 4 + i) * NPS + 208 + lr] = 0;
    }
    f32x4 o[4];
#pragma unroll
    for (int dt = 0; dt < 4; ++dt) { f32x4 z = {0.f, 0.f, 0.f, 0.f}; o[dt] = z; }
    __builtin_amdgcn_s_setprio(1);
#pragma unroll
    for (int jb = 0; jb < 7; ++jb) {
      bf16x8 pf = *(const bf16x8*)(Pw + lr * NPS + jb * 32 + lg * 8);
#pragma unroll
      for (int dt = 0; dt < 4; ++dt) {
        bf16x8 vf = *(const bf16x8*)(Vlds + (dt * 16 + lr) * NPS + jb * 32 + lg * 8);
        o[dt] = __builtin_amdgcn_mfma_f32_16x16x32_bf16(pf, vf, o[dt], 0, 0, 0);
      }
    }
    __builtin_amdgcn_s_setprio(0);
#pragma unroll
    for (int i = 0; i < 4; ++i) {
      const int row = row0 + lg * 4 + i;
      if (row < NTOK) {
        float inv = 1.f / sum4[i];
        size_t base = (size_t)(b * 197 + row) * DIM + h * 64;
#pragma unroll
        for (int dt = 0; dt < 4; ++dt)
          aout[base + dt * 16 + lr] = f2bf(o[dt][i] * inv);
      }
    }
  }
}

extern "C" void kernel_launch(void* const* d_in, const int* in_sizes, int n_in,
                              void* d_out, int out_size, void* d_ws, size_t ws_size,
                              hipStream_t stream) {
  const float* x         = (const float*)d_in[0];
  const float* wqkv      = (const float*)d_in[1];
  const float* q_bias    = (const float*)d_in[2];
  const float* v_bias    = (const float*)d_in[3];
  const float* table     = (const float*)d_in[4];
  const float* wproj     = (const float*)d_in[5];
  const float* proj_bias = (const float*)d_in[6];
  float* out = (float*)d_out;

  char* p = (char*)d_ws;
  short* xb    = (short*)p; p += (size_t)M_PAD * DIM * 2;
  short* wqb   = (short*)p; p += (size_t)3 * DIM * DIM * 2;
  short* wpb   = (short*)p; p += (size_t)DIM * DIM * 2;
  short* qbuf  = (short*)p; p += (size_t)HEADS_TOT * NP * 64 * 2;
  short* kbuf  = (short*)p; p += (size_t)HEADS_TOT * NP * 64 * 2;
  short* vtbuf = (short*)p; p += (size_t)HEADS_TOT * 64 * NP * 2;
  float* rpbf  = (float*)p; p += (size_t)NHEADS * NP * NP * 4;
  short* aout  = xb;  // reuse: xb is dead after gemm_qkv (pad rows stay zero)

  const int conv_tot = (M_ROWS * DIM + 3 * DIM * DIM + DIM * DIM + (M_PAD - M_ROWS) * DIM) / 4;
  convert_kernel<<<(conv_tot + 255) / 256, 256, 0, stream>>>(x, wqkv, wproj, xb, wqb, wpb);
  rpb_kernel<<<(NHEADS * NP * NP + 255) / 256, 256, 0, stream>>>(table, rpbf);
  gemm_qkv_kernel<<<50 * 9, 512, 0, stream>>>(xb, wqb, q_bias, v_bias, qbuf, kbuf, vtbuf);
  attn_kernel<<<HEADS_TOT, 512, 0, stream>>>(qbuf, kbuf, vtbuf, rpbf, aout);
  gemm_proj_kernel<<<50 * 3, 512, 0, stream>>>(aout, wpb, proj_bias, out);
}

// Round 6
// 186.260 us; speedup vs baseline: 1.0690x; 1.0690x over previous
//
#include <hip/hip_runtime.h>
#include <hip/hip_bf16.h>

#define DIM 768
#define NHEADS 12
#define NTOK 197
#define NP 208         // padded tokens (13*16)
#define NPS 232        // VT / P LDS row stride in shorts
#define M_ROWS 12608   // B*N
#define M_PAD 12800    // 50*256
#define HEADS_TOT 768  // B*H
#define NT 24          // K-tiles of 32 (768/32)

typedef __attribute__((ext_vector_type(8))) short bf16x8;
typedef __attribute__((ext_vector_type(4))) float f32x4;

__device__ inline short f2bf(float f) {
  union { __hip_bfloat16 h; short s; } u;
  u.h = __float2bfloat16(f);
  return u.s;
}

__device__ __forceinline__ void gload16(const short* g, short* l) {
  __builtin_amdgcn_global_load_lds((const __attribute__((address_space(1))) void*)g,
                                   (__attribute__((address_space(3))) void*)l, 16, 0, 0);
}

// bijective XCD-aware swizzle (m204)
__device__ __forceinline__ int xcd_swz(int orig, int nwg) {
  int q = nwg >> 3, r = nwg & 7;
  int x = orig & 7, p = orig >> 3;
  return (x < r ? x * (q + 1) : r * (q + 1) + (x - r) * q) + p;
}

// ---------------- convert fp32 -> bf16 (x, qkv_weight, proj_weight) + zero xb pad rows ----------------
__global__ void convert_kernel(const float* __restrict__ x, const float* __restrict__ wq,
                               const float* __restrict__ wp,
                               short* __restrict__ xb, short* __restrict__ wqb,
                               short* __restrict__ wpb) {
  int idx = blockIdx.x * 256 + threadIdx.x;
  const int n_x  = M_ROWS * DIM / 4;
  const int n_wq = 3 * DIM * DIM / 4;
  const int n_wp = DIM * DIM / 4;
  const int n_pad = (M_PAD - M_ROWS) * DIM / 4;
  if (idx >= n_x + n_wq + n_wp) {
    int k = idx - n_x - n_wq - n_wp;
    if (k < n_pad) {
      short4 z = {0, 0, 0, 0};
      *(short4*)(xb + (size_t)M_ROWS * DIM + (size_t)k * 4) = z;
    }
    return;
  }
  const float4* src; short* dst; int off;
  if (idx < n_x)             { src = (const float4*)x;  dst = xb;  off = idx; }
  else if (idx < n_x + n_wq) { src = (const float4*)wq; dst = wqb; off = idx - n_x; }
  else                       { src = (const float4*)wp; dst = wpb; off = idx - n_x - n_wq; }
  float4 v = src[off];
  short4 o;
  o.x = f2bf(v.x); o.y = f2bf(v.y); o.z = f2bf(v.z); o.w = f2bf(v.w);
  *(short4*)(dst + (size_t)off * 4) = o;
}

// ---------------- expand relative position bias to [12][208][208] fp32 ----------------
__global__ void rpb_kernel(const float* __restrict__ table, float* __restrict__ rpbf) {
  int idx = blockIdx.x * 256 + threadIdx.x;
  const int tot = NHEADS * NP * NP;
  if (idx >= tot) return;
  int h = idx / (NP * NP);
  int rem = idx - h * NP * NP;
  int i = rem / NP;
  int j = rem - i * NP;
  float v = 0.f;
  if (i < NTOK && j < NTOK) {
    int t;
    if (i == 0 && j == 0) t = 731;
    else if (i == 0)      t = 729;
    else if (j == 0)      t = 730;
    else {
      int p = i - 1, q = j - 1;
      int ri = p / 14, ci = p - ri * 14;
      int rj = q / 14, cj = q - rj * 14;
      t = (ri - rj + 13) * 27 + (ci - cj + 13);
    }
    v = table[t * NHEADS + h];
  }
  rpbf[idx] = v;
}

// ================= 256x256 pipelined GEMM (BK=32, 4-deep ring, counted vmcnt) =================
// LDS per K-tile buffer (32KB = 16384 shorts): A [2 M-halves][128 rows][4 slots][8], B at +8192.
// Slot rotation by (row>>1)&3: LDS slot sp of row r holds global slot (sp-(r>>1))&3; read
// slot (lg+(lr>>1))&3 -> 2-way banks (free). Per K-tile: 2 phases (M-half x K=32, 16 MFMA),
// each phase stages 2 half-tiles of K-tile kt+3 (buffer (kt-1)&3, last read before the
// barrier ending tile kt-1). One vmcnt(8)+barrier per K-tile; never drain-0 mid-loop.

template<bool DOSTAGE>
__device__ __forceinline__ void ktile256(int kt, short* lds,
                                         const short* Asrc, const short* Bsrc, short* sdst,
                                         int aoff, int boff, f32x4 (&acc)[8][4]) {
  short* base = lds + (kt & 3) * 16384;
  const short* Ab = base + aoff;
  const short* Bb = base + boff;
  short* stg = sdst + ((kt + 3) & 3) * 16384;
  const int kc = (kt + 3) * 32;
  bf16x8 bfr[4];
#pragma unroll
  for (int j = 0; j < 4; ++j) bfr[j] = *(const bf16x8*)(Bb + j * 512);
  // ---- phase 0: M-half 0 ----
  {
    if (DOSTAGE) {
      gload16(Asrc + kc, stg);
      gload16(Bsrc + kc, stg + 8192);
    }
    bf16x8 af[4];
#pragma unroll
    for (int j = 0; j < 4; ++j) af[j] = *(const bf16x8*)(Ab + j * 512);
    __builtin_amdgcn_s_barrier();
    __builtin_amdgcn_s_setprio(1);
#pragma unroll
    for (int j = 0; j < 4; ++j)
#pragma unroll
      for (int n = 0; n < 4; ++n)
        acc[j][n] = __builtin_amdgcn_mfma_f32_16x16x32_bf16(af[j], bfr[n], acc[j][n], 0, 0, 0);
    __builtin_amdgcn_s_setprio(0);
  }
  __builtin_amdgcn_s_barrier();
  // ---- phase 1: M-half 1 ----
  {
    if (DOSTAGE) {
      gload16(Asrc + (size_t)128 * DIM + kc, stg + 4096);
      gload16(Bsrc + (size_t)128 * DIM + kc, stg + 8192 + 4096);
    }
    bf16x8 af[4];
#pragma unroll
    for (int j = 0; j < 4; ++j) af[j] = *(const bf16x8*)(Ab + 2048 + j * 512);
    __builtin_amdgcn_s_barrier();
    __builtin_amdgcn_s_setprio(1);
#pragma unroll
    for (int j = 0; j < 4; ++j)
#pragma unroll
      for (int n = 0; n < 4; ++n)
        acc[4 + j][n] = __builtin_amdgcn_mfma_f32_16x16x32_bf16(af[j], bfr[n], acc[4 + j][n], 0, 0, 0);
    __builtin_amdgcn_s_setprio(0);
  }
  // caller: vmcnt + barrier
}

__device__ __forceinline__ void gemm256_mainloop(const short* __restrict__ A,
                                                 const short* __restrict__ Bw,
                                                 int tm, int tn, short* lds, f32x4 (&acc)[8][4]) {
  const int tid = threadIdx.x;
  const int w = tid >> 6, wm = w >> 2, wn = w & 3;
  const int l = tid & 63, lr = l & 15, lg = l >> 4;
  const int srow = tid >> 2;                         // staging row within half (0..127)
  const int sslot = ((tid & 3) - (tid >> 3)) & 3;    // pre-rotated source slot: (sp-(srow>>1))&3
  const short* Asrc = A + (size_t)(tm * 256 + srow) * DIM + sslot * 8;
  const short* Bsrc = Bw + (size_t)(tn * 256 + srow) * DIM + sslot * 8;
  short* sdst = lds + tid * 8;                       // linear gload_lds dest
  const int slotR = (lg + (lr >> 1)) & 3;            // rotated read slot (per-lane constant)
  const int aoff = wm * 4096 + lr * 32 + slotR * 8;
  const int boff = 8192 + (wn >> 1) * 4096 + ((wn & 1) * 64 + lr) * 32 + slotR * 8;
#pragma unroll
  for (int m = 0; m < 8; ++m)
#pragma unroll
    for (int n = 0; n < 4; ++n) { f32x4 z = {0.f, 0.f, 0.f, 0.f}; acc[m][n] = z; }

  // prologue: stage K-tiles 0,1,2 (12 loads/thread, tile-ordered); wait for tile 0 only
#pragma unroll
  for (int kt = 0; kt < 3; ++kt) {
    gload16(Asrc + kt * 32, sdst + kt * 16384);
    gload16(Bsrc + kt * 32, sdst + kt * 16384 + 8192);
    gload16(Asrc + (size_t)128 * DIM + kt * 32, sdst + kt * 16384 + 4096);
    gload16(Bsrc + (size_t)128 * DIM + kt * 32, sdst + kt * 16384 + 8192 + 4096);
  }
  asm volatile("s_waitcnt vmcnt(8)" ::: "memory");
  __builtin_amdgcn_s_barrier();

  for (int kt = 0; kt < NT - 3; ++kt) {
    ktile256<true>(kt, lds, Asrc, Bsrc, sdst, aoff, boff, acc);
    asm volatile("s_waitcnt vmcnt(8)" ::: "memory");   // kt+1 resident; kt+2,kt+3 in flight
    __builtin_amdgcn_s_barrier();
  }
  ktile256<false>(NT - 3, lds, Asrc, Bsrc, sdst, aoff, boff, acc);
  asm volatile("s_waitcnt vmcnt(4)" ::: "memory");
  __builtin_amdgcn_s_barrier();
  ktile256<false>(NT - 2, lds, Asrc, Bsrc, sdst, aoff, boff, acc);
  asm volatile("s_waitcnt vmcnt(0)" ::: "memory");
  __builtin_amdgcn_s_barrier();
  ktile256<false>(NT - 1, lds, Asrc, Bsrc, sdst, aoff, boff, acc);
}

// ---------------- QKV GEMM (256x256): epilogue scatters to q/k/v^T head-major buffers ----------------
__global__ __launch_bounds__(512)
void gemm_qkv_kernel(const short* __restrict__ xb, const short* __restrict__ wqb,
                     const float* __restrict__ q_bias, const float* __restrict__ v_bias,
                     short* __restrict__ qbuf, short* __restrict__ kbuf,
                     short* __restrict__ vtbuf) {
  __shared__ __attribute__((aligned(16))) short lds[65536];   // 128 KB
  const int wg = xcd_swz(blockIdx.x, 50 * 9);
  const int tn = wg % 9, tm = wg / 9;
  f32x4 acc[8][4];
  gemm256_mainloop(xb, wqb, tm, tn, lds, acc);

  const int tid = threadIdx.x;
  const int w = tid >> 6, wm = w >> 2, wn = w & 3;
  const int l = tid & 63, lr = l & 15, lg = l >> 4;
  const int rbase = tm * 256 + wm * 128, cbase = tn * 256 + wn * 64;
#pragma unroll
  for (int n = 0; n < 4; ++n) {
    int c = cbase + n * 16 + lr;
    int part = (c < 768) ? 0 : ((c < 1536) ? 1 : 2);
    int f = c - part * 768;
    int hh = f >> 6, d = f & 63;
    float bias = (part == 0) ? q_bias[c] : ((part == 2) ? v_bias[f] : 0.f);
#pragma unroll
    for (int m = 0; m < 8; ++m) {
#pragma unroll
      for (int i = 0; i < 4; ++i) {
        int r = rbase + m * 16 + lg * 4 + i;
        if (r < M_ROWS) {
          int b = r / 197, nn = r - b * 197;
          int bh = b * 12 + hh;
          float v = acc[m][n][i] + bias;
          if (part == 0)      qbuf[(size_t)(bh * NP + nn) * 64 + d] = f2bf(v * 0.125f);
          else if (part == 1) kbuf[(size_t)(bh * NP + nn) * 64 + d] = f2bf(v);
          else                vtbuf[(size_t)(bh * 64 + d) * NP + nn] = f2bf(v);
        }
      }
    }
  }
}

// ---- 128x128 2-phase mainloop (round-4, measured 0 conflicts) for proj ----
__device__ inline void gemm_tile_mainloop128(const short* __restrict__ A, const short* __restrict__ Bw,
                                             int tm, int tn,
                                             short* As0, short* Bs0, short* As1, short* Bs1,
                                             f32x4 (&acc)[4][4]) {
  const int tid = threadIdx.x;
  const int l = tid & 63, lr = l & 15, lg = l >> 4;
  const int w = tid >> 6, wm = w >> 1, wn = w & 1;
  const int row = tid >> 2;
  const int c8 = (((tid & 3) ^ ((tid >> 3) & 3)) << 3);   // pre-swizzled source K-slot
  const int rs = (((lg ^ ((lr >> 1) & 3))) << 3);         // swizzled read K-slot
  const short* Ag = A + (size_t)(tm * 128 + row) * DIM + c8;
  const short* Bg = Bw + (size_t)(tn * 128 + row) * DIM + c8;
  const int dOff = tid * 8;
#pragma unroll
  for (int m = 0; m < 4; ++m)
#pragma unroll
    for (int n = 0; n < 4; ++n) { f32x4 z = {0.f, 0.f, 0.f, 0.f}; acc[m][n] = z; }

  gload16(Ag, As0 + dOff);
  gload16(Ag + (size_t)64 * DIM, As0 + 2048 + dOff);
  gload16(Bg, Bs0 + dOff);
  gload16(Bg + (size_t)64 * DIM, Bs0 + 2048 + dOff);
  __syncthreads();

  for (int kt = 0; kt < NT; ++kt) {
    short* Ac = (kt & 1) ? As1 : As0;
    short* Bc = (kt & 1) ? Bs1 : Bs0;
    short* An = (kt & 1) ? As0 : As1;
    short* Bn = (kt & 1) ? Bs0 : Bs1;
    if (kt < NT - 1) {
      gload16(Ag + (kt + 1) * 32, An + dOff);
      gload16(Ag + (size_t)64 * DIM + (kt + 1) * 32, An + 2048 + dOff);
      gload16(Bg + (kt + 1) * 32, Bn + dOff);
      gload16(Bg + (size_t)64 * DIM + (kt + 1) * 32, Bn + 2048 + dOff);
    }
    bf16x8 af[4], bfr[4];
#pragma unroll
    for (int m = 0; m < 4; ++m)
      af[m] = *(const bf16x8*)(Ac + (wm * 64 + m * 16 + lr) * 32 + rs);
#pragma unroll
    for (int n = 0; n < 4; ++n)
      bfr[n] = *(const bf16x8*)(Bc + (wn * 64 + n * 16 + lr) * 32 + rs);
#pragma unroll
    for (int m = 0; m < 4; ++m)
#pragma unroll
      for (int n = 0; n < 4; ++n)
        acc[m][n] = __builtin_amdgcn_mfma_f32_16x16x32_bf16(af[m], bfr[n], acc[m][n], 0, 0, 0);
    __syncthreads();
  }
}

// ---------------- proj GEMM (128x128): fp32 out + bias ----------------
__global__ void gemm_proj_kernel(const short* __restrict__ ab, const short* __restrict__ wpb,
                                 const float* __restrict__ proj_bias, float* __restrict__ out) {
  __shared__ __attribute__((aligned(16))) short As0[128 * 32];
  __shared__ __attribute__((aligned(16))) short Bs0[128 * 32];
  __shared__ __attribute__((aligned(16))) short As1[128 * 32];
  __shared__ __attribute__((aligned(16))) short Bs1[128 * 32];
  const int wg = xcd_swz(blockIdx.x, 99 * 6);
  const int tn = wg % 6, tm = wg / 6;
  f32x4 acc[4][4];
  gemm_tile_mainloop128(ab, wpb, tm, tn, As0, Bs0, As1, Bs1, acc);

  const int tid = threadIdx.x;
  const int w = tid >> 6, l = tid & 63, lr = l & 15, lg = l >> 4;
  const int wm = w >> 1, wn = w & 1;
  const int rbase = tm * 128 + wm * 64, cbase = tn * 128 + wn * 64;
#pragma unroll
  for (int n = 0; n < 4; ++n) {
    int c = cbase + n * 16 + lr;
    float pb = proj_bias[c];
#pragma unroll
    for (int m = 0; m < 4; ++m) {
#pragma unroll
      for (int i = 0; i < 4; ++i) {
        int r = rbase + m * 16 + lg * 4 + i;
        if (r < M_ROWS) out[(size_t)r * DIM + c] = acc[m][n][i] + pb;
      }
    }
  }
}

// ---------------- attention: one block (8 waves) per (b,h), K/V^T LDS-resident ----------------
__global__ __launch_bounds__(512, 1)
void attn_kernel(const short* __restrict__ qbuf, const short* __restrict__ kbuf,
                 const short* __restrict__ vtbuf, const float* __restrict__ rpbf,
                 short* __restrict__ aout) {
  __shared__ __attribute__((aligned(16))) short Klds[208 * 64];
  __shared__ __attribute__((aligned(16))) short Vlds[64 * NPS];
  __shared__ __attribute__((aligned(16))) short Plds[8 * 16 * NPS];
  const int bh = blockIdx.x;
  const int b = bh / 12, h = bh - b * 12;
  const short* Qg = qbuf + (size_t)bh * NP * 64;
  const short* Kg = kbuf + (size_t)bh * NP * 64;
  const short* Vg = vtbuf + (size_t)bh * 64 * NP;
  const float* RP = rpbf + (size_t)h * NP * NP;
  const int tid = threadIdx.x;
  const int wave = tid >> 6, l = tid & 63, lr = l & 15, lg = l >> 4;

  for (int c = tid; c < 1664; c += 512) {
    int r = c >> 3, sp = c & 7;
    gload16(Kg + r * 64 + ((sp ^ (r & 7)) << 3), Klds + c * 8);
  }
  for (int c = tid; c < 64 * 29; c += 512) {
    int r = c / 29, sp = c - r * 29;
    int sg = sp < 26 ? sp : 25;
    gload16(Vg + r * NP + sg * 8, Vlds + c * 8);
  }
  __syncthreads();
  if (tid < 64) {
    for (int j = NTOK; j < NPS; ++j) Vlds[tid * NPS + j] = 0;
  }
  __syncthreads();

  short* Pw = Plds + wave * 16 * NPS;
  for (int s = wave; s < 13; s += 8) {
    const int row0 = s * 16;
    bf16x8 qf0 = *(const bf16x8*)(Qg + (row0 + lr) * 64 + lg * 8);
    bf16x8 qf1 = *(const bf16x8*)(Qg + (row0 + lr) * 64 + 32 + lg * 8);
    f32x4 acc[13];
#pragma unroll
    for (int t = 0; t < 13; ++t) { f32x4 z = {0.f, 0.f, 0.f, 0.f}; acc[t] = z; }
    __builtin_amdgcn_s_setprio(1);
#pragma unroll
    for (int t = 0; t < 13; ++t) {
      int rk = t * 16 + lr;
      int sw = lr & 7;
      bf16x8 kf0 = *(const bf16x8*)(Klds + rk * 64 + ((lg ^ sw) << 3));
      bf16x8 kf1 = *(const bf16x8*)(Klds + rk * 64 + (((4 + lg) ^ sw) << 3));
      acc[t] = __builtin_amdgcn_mfma_f32_16x16x32_bf16(qf0, kf0, acc[t], 0, 0, 0);
      acc[t] = __builtin_amdgcn_mfma_f32_16x16x32_bf16(qf1, kf1, acc[t], 0, 0, 0);
    }
    __builtin_amdgcn_s_setprio(0);
    float sum4[4];
#pragma unroll
    for (int i = 0; i < 4; ++i) {
      const int row = row0 + lg * 4 + i;
      const float* rp = RP + (size_t)row * NP;
      float sv[13];
      float mx = -3e38f;
#pragma unroll
      for (int t = 0; t < 13; ++t) {
        int col = t * 16 + lr;
        float s_ = (col < NTOK) ? (acc[t][i] + rp[col]) : -3e38f;
        sv[t] = s_;
        mx = fmaxf(mx, s_);
      }
      mx = fmaxf(mx, __shfl_xor(mx, 1, 16));
      mx = fmaxf(mx, __shfl_xor(mx, 2, 16));
      mx = fmaxf(mx, __shfl_xor(mx, 4, 16));
      mx = fmaxf(mx, __shfl_xor(mx, 8, 16));
      float sm = 0.f;
#pragma unroll
      for (int t = 0; t < 13; ++t) {
        float p = __expf(sv[t] - mx);
        sm += p;
        Pw[(lg * 4 + i) * NPS + t * 16 + lr] = f2bf(p);
      }
      sm += __shfl_xor(sm, 1, 16);
      sm += __shfl_xor(sm, 2, 16);
      sm += __shfl_xor(sm, 4, 16);
      sm += __shfl_xor(sm, 8, 16);
      sum4[i] = sm;
      Pw[(lg * 4 + i) * NPS + 208 + lr] = 0;
    }
    f32x4 o[4];
#pragma unroll
    for (int dt = 0; dt < 4; ++dt) { f32x4 z = {0.f, 0.f, 0.f, 0.f}; o[dt] = z; }
    __builtin_amdgcn_s_setprio(1);
#pragma unroll
    for (int jb = 0; jb < 7; ++jb) {
      bf16x8 pf = *(const bf16x8*)(Pw + lr * NPS + jb * 32 + lg * 8);
#pragma unroll
      for (int dt = 0; dt < 4; ++dt) {
        bf16x8 vf = *(const bf16x8*)(Vlds + (dt * 16 + lr) * NPS + jb * 32 + lg * 8);
        o[dt] = __builtin_amdgcn_mfma_f32_16x16x32_bf16(pf, vf, o[dt], 0, 0, 0);
      }
    }
    __builtin_amdgcn_s_setprio(0);
#pragma unroll
    for (int i = 0; i < 4; ++i) {
      const int row = row0 + lg * 4 + i;
      if (row < NTOK) {
        float inv = 1.f / sum4[i];
        size_t base = (size_t)(b * 197 + row) * DIM + h * 64;
#pragma unroll
        for (int dt = 0; dt < 4; ++dt)
          aout[base + dt * 16 + lr] = f2bf(o[dt][i] * inv);
      }
    }
  }
}

extern "C" void kernel_launch(void* const* d_in, const int* in_sizes, int n_in,
                              void* d_out, int out_size, void* d_ws, size_t ws_size,
                              hipStream_t stream) {
  const float* x         = (const float*)d_in[0];
  const float* wqkv      = (const float*)d_in[1];
  const float* q_bias    = (const float*)d_in[2];
  const float* v_bias    = (const float*)d_in[3];
  const float* table     = (const float*)d_in[4];
  const float* wproj     = (const float*)d_in[5];
  const float* proj_bias = (const float*)d_in[6];
  float* out = (float*)d_out;

  char* p = (char*)d_ws;
  short* xb    = (short*)p; p += (size_t)M_PAD * DIM * 2;
  short* wqb   = (short*)p; p += (size_t)3 * DIM * DIM * 2;
  short* wpb   = (short*)p; p += (size_t)DIM * DIM * 2;
  short* qbuf  = (short*)p; p += (size_t)HEADS_TOT * NP * 64 * 2;
  short* kbuf  = (short*)p; p += (size_t)HEADS_TOT * NP * 64 * 2;
  short* vtbuf = (short*)p; p += (size_t)HEADS_TOT * 64 * NP * 2;
  float* rpbf  = (float*)p; p += (size_t)NHEADS * NP * NP * 4;
  short* aout  = xb;  // reuse: xb is dead after gemm_qkv (pad rows stay zero)

  const int conv_tot = (M_ROWS * DIM + 3 * DIM * DIM + DIM * DIM + (M_PAD - M_ROWS) * DIM) / 4;
  convert_kernel<<<(conv_tot + 255) / 256, 256, 0, stream>>>(x, wqkv, wproj, xb, wqb, wpb);
  rpb_kernel<<<(NHEADS * NP * NP + 255) / 256, 256, 0, stream>>>(table, rpbf);
  gemm_qkv_kernel<<<50 * 9, 512, 0, stream>>>(xb, wqb, q_bias, v_bias, qbuf, kbuf, vtbuf);
  attn_kernel<<<HEADS_TOT, 512, 0, stream>>>(qbuf, kbuf, vtbuf, rpbf, aout);
  gemm_proj_kernel<<<99 * 6, 256, 0, stream>>>(aout, wpb, proj_bias, out);
}

// Round 7
// 159.036 us; speedup vs baseline: 1.2520x; 1.1712x over previous
//
#include <hip/hip_runtime.h>
#include <hip/hip_bf16.h>

#define DIM 768
#define QKVD 2304      // 3*DIM
#define NHEADS 12
#define NTOK 197
#define NP 208         // padded tokens (13*16)
#define NPS 232        // VT / P LDS row stride in shorts
#define M_ROWS 12608   // B*N
#define M_PAD 12800    // 100*128
#define HEADS_TOT 768  // B*H
#define NT 24          // K-tiles of 32 (768/32)

typedef __attribute__((ext_vector_type(8))) short bf16x8;
typedef __attribute__((ext_vector_type(4))) float f32x4;

__device__ inline short f2bf(float f) {
  union { __hip_bfloat16 h; short s; } u;
  u.h = __float2bfloat16(f);
  return u.s;
}

__device__ __forceinline__ void gload16(const short* g, short* l) {
  __builtin_amdgcn_global_load_lds((const __attribute__((address_space(1))) void*)g,
                                   (__attribute__((address_space(3))) void*)l, 16, 0, 0);
}

// bijective XCD-aware swizzle (m204)
__device__ __forceinline__ int xcd_swz(int orig, int nwg) {
  int q = nwg >> 3, r = nwg & 7;
  int x = orig & 7, p = orig >> 3;
  return (x < r ? x * (q + 1) : r * (q + 1) + (x - r) * q) + p;
}

// ---------------- convert fp32 -> bf16 (x, qkv_weight, proj_weight) + zero xb pad rows ----------------
__global__ void convert_kernel(const float* __restrict__ x, const float* __restrict__ wq,
                               const float* __restrict__ wp,
                               short* __restrict__ xb, short* __restrict__ wqb,
                               short* __restrict__ wpb) {
  int idx = blockIdx.x * 256 + threadIdx.x;
  const int n_x  = M_ROWS * DIM / 4;
  const int n_wq = 3 * DIM * DIM / 4;
  const int n_wp = DIM * DIM / 4;
  const int n_pad = (M_PAD - M_ROWS) * DIM / 4;
  if (idx >= n_x + n_wq + n_wp) {
    int k = idx - n_x - n_wq - n_wp;
    if (k < n_pad) {
      short4 z = {0, 0, 0, 0};
      *(short4*)(xb + (size_t)M_ROWS * DIM + (size_t)k * 4) = z;
    }
    return;
  }
  const float4* src; short* dst; int off;
  if (idx < n_x)             { src = (const float4*)x;  dst = xb;  off = idx; }
  else if (idx < n_x + n_wq) { src = (const float4*)wq; dst = wqb; off = idx - n_x; }
  else                       { src = (const float4*)wp; dst = wpb; off = idx - n_x - n_wq; }
  float4 v = src[off];
  short4 o;
  o.x = f2bf(v.x); o.y = f2bf(v.y); o.z = f2bf(v.z); o.w = f2bf(v.w);
  *(short4*)(dst + (size_t)off * 4) = o;
}

// ---------------- expand relative position bias to [12][208][208] fp32 ----------------
__global__ void rpb_kernel(const float* __restrict__ table, float* __restrict__ rpbf) {
  int idx = blockIdx.x * 256 + threadIdx.x;
  const int tot = NHEADS * NP * NP;
  if (idx >= tot) return;
  int h = idx / (NP * NP);
  int rem = idx - h * NP * NP;
  int i = rem / NP;
  int j = rem - i * NP;
  float v = 0.f;
  if (i < NTOK && j < NTOK) {
    int t;
    if (i == 0 && j == 0) t = 731;
    else if (i == 0)      t = 729;
    else if (j == 0)      t = 730;
    else {
      int p = i - 1, q = j - 1;
      int ri = p / 14, ci = p - ri * 14;
      int rj = q / 14, cj = q - rj * 14;
      t = (ri - rj + 13) * 27 + (ci - cj + 13);
    }
    v = table[t * NHEADS + h];
  }
  rpbf[idx] = v;
}

// ---- 128x128 2-phase dbuf mainloop, 0-conflict XOR slot swizzle (round-4 proven) ----
__device__ inline void gemm_tile_mainloop128(const short* __restrict__ A, const short* __restrict__ Bw,
                                             int tm, int tn,
                                             short* As0, short* Bs0, short* As1, short* Bs1,
                                             f32x4 (&acc)[4][4]) {
  const int tid = threadIdx.x;
  const int l = tid & 63, lr = l & 15, lg = l >> 4;
  const int w = tid >> 6, wm = w >> 1, wn = w & 1;
  const int row = tid >> 2;
  const int c8 = (((tid & 3) ^ ((tid >> 3) & 3)) << 3);   // pre-swizzled source K-slot
  const int rs = (((lg ^ ((lr >> 1) & 3))) << 3);         // swizzled read K-slot
  const short* Ag = A + (size_t)(tm * 128 + row) * DIM + c8;
  const short* Bg = Bw + (size_t)(tn * 128 + row) * DIM + c8;
  const int dOff = tid * 8;
#pragma unroll
  for (int m = 0; m < 4; ++m)
#pragma unroll
    for (int n = 0; n < 4; ++n) { f32x4 z = {0.f, 0.f, 0.f, 0.f}; acc[m][n] = z; }

  gload16(Ag, As0 + dOff);
  gload16(Ag + (size_t)64 * DIM, As0 + 2048 + dOff);
  gload16(Bg, Bs0 + dOff);
  gload16(Bg + (size_t)64 * DIM, Bs0 + 2048 + dOff);
  __syncthreads();

  for (int kt = 0; kt < NT; ++kt) {
    short* Ac = (kt & 1) ? As1 : As0;
    short* Bc = (kt & 1) ? Bs1 : Bs0;
    short* An = (kt & 1) ? As0 : As1;
    short* Bn = (kt & 1) ? Bs0 : Bs1;
    if (kt < NT - 1) {
      gload16(Ag + (kt + 1) * 32, An + dOff);
      gload16(Ag + (size_t)64 * DIM + (kt + 1) * 32, An + 2048 + dOff);
      gload16(Bg + (kt + 1) * 32, Bn + dOff);
      gload16(Bg + (size_t)64 * DIM + (kt + 1) * 32, Bn + 2048 + dOff);
    }
    bf16x8 af[4], bfr[4];
#pragma unroll
    for (int m = 0; m < 4; ++m)
      af[m] = *(const bf16x8*)(Ac + (wm * 64 + m * 16 + lr) * 32 + rs);
#pragma unroll
    for (int n = 0; n < 4; ++n)
      bfr[n] = *(const bf16x8*)(Bc + (wn * 64 + n * 16 + lr) * 32 + rs);
#pragma unroll
    for (int m = 0; m < 4; ++m)
#pragma unroll
      for (int n = 0; n < 4; ++n)
        acc[m][n] = __builtin_amdgcn_mfma_f32_16x16x32_bf16(af[m], bfr[n], acc[m][n], 0, 0, 0);
    __syncthreads();
  }
}

// ---------------- QKV GEMM: PURE row-major bf16 out, bias+scale folded ----------------
__global__ void gemm_qkv_kernel(const short* __restrict__ xb, const short* __restrict__ wqb,
                                const float* __restrict__ q_bias, const float* __restrict__ v_bias,
                                short* __restrict__ qkvb) {
  __shared__ __attribute__((aligned(16))) short As0[128 * 32];
  __shared__ __attribute__((aligned(16))) short Bs0[128 * 32];
  __shared__ __attribute__((aligned(16))) short As1[128 * 32];
  __shared__ __attribute__((aligned(16))) short Bs1[128 * 32];
  const int wg = xcd_swz(blockIdx.x, 100 * 18);
  const int tn = wg % 18, tm = wg / 18;   // tn fastest: A-tile L2-reuse
  f32x4 acc[4][4];
  gemm_tile_mainloop128(xb, wqb, tm, tn, As0, Bs0, As1, Bs1, acc);

  const int tid = threadIdx.x;
  const int w = tid >> 6, l = tid & 63, lr = l & 15, lg = l >> 4;
  const int wm = w >> 1, wn = w & 1;
  const int rbase = tm * 128 + wm * 64, cbase = tn * 128 + wn * 64;
#pragma unroll
  for (int n = 0; n < 4; ++n) {
    int c = cbase + n * 16 + lr;
    int part = (c < 768) ? 0 : ((c < 1536) ? 1 : 2);
    float bias = (part == 0) ? q_bias[c] : ((part == 2) ? v_bias[c - 1536] : 0.f);
    float scl = (part == 0) ? 0.125f : 1.f;
#pragma unroll
    for (int m = 0; m < 4; ++m) {
#pragma unroll
      for (int i = 0; i < 4; ++i) {
        int r = rbase + m * 16 + lg * 4 + i;
        qkvb[(size_t)r * QKVD + c] = f2bf((acc[m][n][i] + bias) * scl);
      }
    }
  }
}

// ---------------- attention: one block (8 waves) per (b,h), reads qkvb directly ----------------
__global__ __launch_bounds__(512, 1)
void attn_kernel(const short* __restrict__ qkvb, const float* __restrict__ rpbf,
                 short* __restrict__ aout) {
  __shared__ __attribute__((aligned(16))) short Klds[208 * 64];      // XOR-swizzled slots
  __shared__ __attribute__((aligned(16))) short Vlds[64 * NPS];      // V^T
  __shared__ __attribute__((aligned(16))) short Plds[8 * 16 * NPS];
  const int bh = blockIdx.x;
  const int b = bh / 12, h = bh - b * 12;
  const short* base = qkvb + (size_t)(b * 197) * QKVD;
  const short* Qg = base + h * 64;
  const short* Kg = base + 768 + h * 64;
  const short* Vg = base + 1536 + h * 64;
  const float* RP = rpbf + (size_t)h * NP * NP;
  const int tid = threadIdx.x;
  const int wave = tid >> 6, l = tid & 63, lr = l & 15, lg = l >> 4;

  // stage K swizzled (row-clamped: pad rows duplicate row 196, zero-weighted later)
  for (int c = tid; c < 1664; c += 512) {
    int r = c >> 3, sp = c & 7;
    int rr = r < NTOK ? r : NTOK - 1;
    gload16(Kg + (size_t)rr * QKVD + ((sp ^ (r & 7)) << 3), Klds + c * 8);
  }
  // stage V transposed: read [t][d] coalesced, ds_write [d][t]
  for (int idx = tid; idx < 64 * NP; idx += 512) {
    int t = idx >> 6, d = idx & 63;
    int tt = t < NTOK ? t : NTOK - 1;
    Vlds[d * NPS + t] = Vg[(size_t)tt * QKVD + d];
  }
  __syncthreads();
  if (tid < 64) {
    for (int j = NP; j < NPS; ++j) Vlds[tid * NPS + j] = 0;  // pad cols of V^T
  }
  __syncthreads();

  short* Pw = Plds + wave * 16 * NPS;
  for (int s = wave; s < 13; s += 8) {
    const int row0 = s * 16;
    const int qrow = (row0 + lr < NTOK) ? (row0 + lr) : (NTOK - 1);
    bf16x8 qf0 = *(const bf16x8*)(Qg + (size_t)qrow * QKVD + lg * 8);
    bf16x8 qf1 = *(const bf16x8*)(Qg + (size_t)qrow * QKVD + 32 + lg * 8);
    f32x4 acc[13];
#pragma unroll
    for (int t = 0; t < 13; ++t) { f32x4 z = {0.f, 0.f, 0.f, 0.f}; acc[t] = z; }
    __builtin_amdgcn_s_setprio(1);
#pragma unroll
    for (int t = 0; t < 13; ++t) {
      int rk = t * 16 + lr;
      int sw = lr & 7;
      bf16x8 kf0 = *(const bf16x8*)(Klds + rk * 64 + ((lg ^ sw) << 3));
      bf16x8 kf1 = *(const bf16x8*)(Klds + rk * 64 + (((4 + lg) ^ sw) << 3));
      acc[t] = __builtin_amdgcn_mfma_f32_16x16x32_bf16(qf0, kf0, acc[t], 0, 0, 0);
      acc[t] = __builtin_amdgcn_mfma_f32_16x16x32_bf16(qf1, kf1, acc[t], 0, 0, 0);
    }
    __builtin_amdgcn_s_setprio(0);
    float sum4[4];
#pragma unroll
    for (int i = 0; i < 4; ++i) {
      const int row = row0 + lg * 4 + i;
      const float* rp = RP + (size_t)row * NP;
      float sv[13];
      float mx = -3e38f;
#pragma unroll
      for (int t = 0; t < 13; ++t) {
        int col = t * 16 + lr;
        float s_ = (col < NTOK) ? (acc[t][i] + rp[col]) : -3e38f;
        sv[t] = s_;
        mx = fmaxf(mx, s_);
      }
      mx = fmaxf(mx, __shfl_xor(mx, 1, 16));
      mx = fmaxf(mx, __shfl_xor(mx, 2, 16));
      mx = fmaxf(mx, __shfl_xor(mx, 4, 16));
      mx = fmaxf(mx, __shfl_xor(mx, 8, 16));
      float sm = 0.f;
#pragma unroll
      for (int t = 0; t < 13; ++t) {
        float p = __expf(sv[t] - mx);
        sm += p;
        Pw[(lg * 4 + i) * NPS + t * 16 + lr] = f2bf(p);
      }
      sm += __shfl_xor(sm, 1, 16);
      sm += __shfl_xor(sm, 2, 16);
      sm += __shfl_xor(sm, 4, 16);
      sm += __shfl_xor(sm, 8, 16);
      sum4[i] = sm;
      Pw[(lg * 4 + i) * NPS + 208 + lr] = 0;
    }
    f32x4 o[4];
#pragma unroll
    for (int dt = 0; dt < 4; ++dt) { f32x4 z = {0.f, 0.f, 0.f, 0.f}; o[dt] = z; }
    __builtin_amdgcn_s_setprio(1);
#pragma unroll
    for (int jb = 0; jb < 7; ++jb) {
      bf16x8 pf = *(const bf16x8*)(Pw + lr * NPS + jb * 32 + lg * 8);
#pragma unroll
      for (int dt = 0; dt < 4; ++dt) {
        bf16x8 vf = *(const bf16x8*)(Vlds + (dt * 16 + lr) * NPS + jb * 32 + lg * 8);
        o[dt] = __builtin_amdgcn_mfma_f32_16x16x32_bf16(pf, vf, o[dt], 0, 0, 0);
      }
    }
    __builtin_amdgcn_s_setprio(0);
#pragma unroll
    for (int i = 0; i < 4; ++i) {
      const int row = row0 + lg * 4 + i;
      if (row < NTOK) {
        float inv = 1.f / sum4[i];
        size_t base2 = (size_t)(b * 197 + row) * DIM + h * 64;
#pragma unroll
        for (int dt = 0; dt < 4; ++dt)
          aout[base2 + dt * 16 + lr] = f2bf(o[dt][i] * inv);
      }
    }
  }
}

// ---------------- proj GEMM (128x128): fp32 out + bias ----------------
__global__ void gemm_proj_kernel(const short* __restrict__ ab, const short* __restrict__ wpb,
                                 const float* __restrict__ proj_bias, float* __restrict__ out) {
  __shared__ __attribute__((aligned(16))) short As0[128 * 32];
  __shared__ __attribute__((aligned(16))) short Bs0[128 * 32];
  __shared__ __attribute__((aligned(16))) short As1[128 * 32];
  __shared__ __attribute__((aligned(16))) short Bs1[128 * 32];
  const int wg = xcd_swz(blockIdx.x, 99 * 6);
  const int tn = wg % 6, tm = wg / 6;
  f32x4 acc[4][4];
  gemm_tile_mainloop128(ab, wpb, tm, tn, As0, Bs0, As1, Bs1, acc);

  const int tid = threadIdx.x;
  const int w = tid >> 6, l = tid & 63, lr = l & 15, lg = l >> 4;
  const int wm = w >> 1, wn = w & 1;
  const int rbase = tm * 128 + wm * 64, cbase = tn * 128 + wn * 64;
#pragma unroll
  for (int n = 0; n < 4; ++n) {
    int c = cbase + n * 16 + lr;
    float pb = proj_bias[c];
#pragma unroll
    for (int m = 0; m < 4; ++m) {
#pragma unroll
      for (int i = 0; i < 4; ++i) {
        int r = rbase + m * 16 + lg * 4 + i;
        if (r < M_ROWS) out[(size_t)r * DIM + c] = acc[m][n][i] + pb;
      }
    }
  }
}

extern "C" void kernel_launch(void* const* d_in, const int* in_sizes, int n_in,
                              void* d_out, int out_size, void* d_ws, size_t ws_size,
                              hipStream_t stream) {
  const float* x         = (const float*)d_in[0];
  const float* wqkv      = (const float*)d_in[1];
  const float* q_bias    = (const float*)d_in[2];
  const float* v_bias    = (const float*)d_in[3];
  const float* table     = (const float*)d_in[4];
  const float* wproj     = (const float*)d_in[5];
  const float* proj_bias = (const float*)d_in[6];
  float* out = (float*)d_out;

  char* p = (char*)d_ws;
  short* xb    = (short*)p; p += (size_t)M_PAD * DIM * 2;       // 19.7 MB
  short* wqb   = (short*)p; p += (size_t)3 * DIM * DIM * 2;     //  3.5 MB
  short* wpb   = (short*)p; p += (size_t)DIM * DIM * 2;         //  1.2 MB
  short* qkvb  = (short*)p; p += (size_t)M_PAD * QKVD * 2;      // 59.0 MB
  float* rpbf  = (float*)p; p += (size_t)NHEADS * NP * NP * 4;  //  2.1 MB
  short* aout  = xb;  // reuse: xb is dead after gemm_qkv (pad rows stay zero)

  const int conv_tot = (M_ROWS * DIM + 3 * DIM * DIM + DIM * DIM + (M_PAD - M_ROWS) * DIM) / 4;
  convert_kernel<<<(conv_tot + 255) / 256, 256, 0, stream>>>(x, wqkv, wproj, xb, wqb, wpb);
  rpb_kernel<<<(NHEADS * NP * NP + 255) / 256, 256, 0, stream>>>(table, rpbf);
  gemm_qkv_kernel<<<100 * 18, 256, 0, stream>>>(xb, wqb, q_bias, v_bias, qkvb);
  attn_kernel<<<HEADS_TOT, 512, 0, stream>>>(qkvb, rpbf, aout);
  gemm_proj_kernel<<<99 * 6, 256, 0, stream>>>(aout, wpb, proj_bias, out);
}

// Round 8
// 149.610 us; speedup vs baseline: 1.3309x; 1.0630x over previous
//
#include <hip/hip_runtime.h>
#include <hip/hip_bf16.h>

#define DIM 768
#define QKVD 2304      // 3*DIM
#define NHEADS 12
#define NTOK 197
#define NP 208         // padded tokens (13*16)
#define NPS 232        // VT / P LDS row stride in shorts
#define M_ROWS 12608   // B*N
#define M_PAD 12800    // 100*128 = 50*256
#define HEADS_TOT 768  // B*H
#define NT 24          // K-tiles of 32 (768/32)

typedef __attribute__((ext_vector_type(8))) short bf16x8;
typedef __attribute__((ext_vector_type(4))) float f32x4;

__device__ inline short f2bf(float f) {
  union { __hip_bfloat16 h; short s; } u;
  u.h = __float2bfloat16(f);
  return u.s;
}

__device__ __forceinline__ void gload16(const short* g, short* l) {
  __builtin_amdgcn_global_load_lds((const __attribute__((address_space(1))) void*)g,
                                   (__attribute__((address_space(3))) void*)l, 16, 0, 0);
}

// bijective XCD-aware swizzle (m204)
__device__ __forceinline__ int xcd_swz(int orig, int nwg) {
  int q = nwg >> 3, r = nwg & 7;
  int x = orig & 7, p = orig >> 3;
  return (x < r ? x * (q + 1) : r * (q + 1) + (x - r) * q) + p;
}

// ---------------- convert fp32 -> bf16 (x, qkv_weight, proj_weight) + zero xb pad rows ----------------
__global__ void convert_kernel(const float* __restrict__ x, const float* __restrict__ wq,
                               const float* __restrict__ wp,
                               short* __restrict__ xb, short* __restrict__ wqb,
                               short* __restrict__ wpb) {
  int idx = blockIdx.x * 256 + threadIdx.x;
  const int n_x  = M_ROWS * DIM / 4;
  const int n_wq = 3 * DIM * DIM / 4;
  const int n_wp = DIM * DIM / 4;
  const int n_pad = (M_PAD - M_ROWS) * DIM / 4;
  if (idx >= n_x + n_wq + n_wp) {
    int k = idx - n_x - n_wq - n_wp;
    if (k < n_pad) {
      short4 z = {0, 0, 0, 0};
      *(short4*)(xb + (size_t)M_ROWS * DIM + (size_t)k * 4) = z;
    }
    return;
  }
  const float4* src; short* dst; int off;
  if (idx < n_x)             { src = (const float4*)x;  dst = xb;  off = idx; }
  else if (idx < n_x + n_wq) { src = (const float4*)wq; dst = wqb; off = idx - n_x; }
  else                       { src = (const float4*)wp; dst = wpb; off = idx - n_x - n_wq; }
  float4 v = src[off];
  short4 o;
  o.x = f2bf(v.x); o.y = f2bf(v.y); o.z = f2bf(v.z); o.w = f2bf(v.w);
  *(short4*)(dst + (size_t)off * 4) = o;
}

// ---------------- expand relative position bias to [12][208][208] fp32 ----------------
__global__ void rpb_kernel(const float* __restrict__ table, float* __restrict__ rpbf) {
  int idx = blockIdx.x * 256 + threadIdx.x;
  const int tot = NHEADS * NP * NP;
  if (idx >= tot) return;
  int h = idx / (NP * NP);
  int rem = idx - h * NP * NP;
  int i = rem / NP;
  int j = rem - i * NP;
  float v = 0.f;
  if (i < NTOK && j < NTOK) {
    int t;
    if (i == 0 && j == 0) t = 731;
    else if (i == 0)      t = 729;
    else if (j == 0)      t = 730;
    else {
      int p = i - 1, q = j - 1;
      int ri = p / 14, ci = p - ri * 14;
      int rj = q / 14, cj = q - rj * 14;
      t = (ri - rj + 13) * 27 + (ci - cj + 13);
    }
    v = table[t * NHEADS + h];
  }
  rpbf[idx] = v;
}

// ================= 256x256 pipelined GEMM (BK=32, 4-deep ring, counted vmcnt) =================
// (round-6 mainloop, verified race-correct + 0 bank conflicts)
template<bool DOSTAGE>
__device__ __forceinline__ void ktile256(int kt, short* lds,
                                         const short* Asrc, const short* Bsrc, short* sdst,
                                         int aoff, int boff, f32x4 (&acc)[8][4]) {
  short* base = lds + (kt & 3) * 16384;
  const short* Ab = base + aoff;
  const short* Bb = base + boff;
  short* stg = sdst + ((kt + 3) & 3) * 16384;
  const int kc = (kt + 3) * 32;
  bf16x8 bfr[4];
#pragma unroll
  for (int j = 0; j < 4; ++j) bfr[j] = *(const bf16x8*)(Bb + j * 512);
  // ---- phase 0: M-half 0 ----
  {
    if (DOSTAGE) {
      gload16(Asrc + kc, stg);
      gload16(Bsrc + kc, stg + 8192);
    }
    bf16x8 af[4];
#pragma unroll
    for (int j = 0; j < 4; ++j) af[j] = *(const bf16x8*)(Ab + j * 512);
    __builtin_amdgcn_s_barrier();
    __builtin_amdgcn_s_setprio(1);
#pragma unroll
    for (int j = 0; j < 4; ++j)
#pragma unroll
      for (int n = 0; n < 4; ++n)
        acc[j][n] = __builtin_amdgcn_mfma_f32_16x16x32_bf16(af[j], bfr[n], acc[j][n], 0, 0, 0);
    __builtin_amdgcn_s_setprio(0);
  }
  __builtin_amdgcn_s_barrier();
  // ---- phase 1: M-half 1 ----
  {
    if (DOSTAGE) {
      gload16(Asrc + (size_t)128 * DIM + kc, stg + 4096);
      gload16(Bsrc + (size_t)128 * DIM + kc, stg + 8192 + 4096);
    }
    bf16x8 af[4];
#pragma unroll
    for (int j = 0; j < 4; ++j) af[j] = *(const bf16x8*)(Ab + 2048 + j * 512);
    __builtin_amdgcn_s_barrier();
    __builtin_amdgcn_s_setprio(1);
#pragma unroll
    for (int j = 0; j < 4; ++j)
#pragma unroll
      for (int n = 0; n < 4; ++n)
        acc[4 + j][n] = __builtin_amdgcn_mfma_f32_16x16x32_bf16(af[j], bfr[n], acc[4 + j][n], 0, 0, 0);
    __builtin_amdgcn_s_setprio(0);
  }
  // caller: vmcnt + barrier
}

__device__ __forceinline__ void gemm256_mainloop(const short* __restrict__ A,
                                                 const short* __restrict__ Bw,
                                                 int tm, int tn, short* lds, f32x4 (&acc)[8][4]) {
  const int tid = threadIdx.x;
  const int srow = tid >> 2;                         // staging row within half (0..127)
  const int sslot = ((tid & 3) - (tid >> 3)) & 3;    // pre-rotated source slot: (sp-(srow>>1))&3
  const int l = tid & 63, lr = l & 15, lg = l >> 4;
  const int w = tid >> 6, wm = w >> 2, wn = w & 3;
  const short* Asrc = A + (size_t)(tm * 256 + srow) * DIM + sslot * 8;
  const short* Bsrc = Bw + (size_t)(tn * 256 + srow) * DIM + sslot * 8;
  short* sdst = lds + tid * 8;                       // linear gload_lds dest
  const int slotR = (lg + (lr >> 1)) & 3;            // rotated read slot (per-lane constant)
  const int aoff = wm * 4096 + lr * 32 + slotR * 8;
  const int boff = 8192 + (wn >> 1) * 4096 + ((wn & 1) * 64 + lr) * 32 + slotR * 8;
#pragma unroll
  for (int m = 0; m < 8; ++m)
#pragma unroll
    for (int n = 0; n < 4; ++n) { f32x4 z = {0.f, 0.f, 0.f, 0.f}; acc[m][n] = z; }

  // prologue: stage K-tiles 0,1,2 (12 loads/thread, tile-ordered); wait for tile 0 only
#pragma unroll
  for (int kt = 0; kt < 3; ++kt) {
    gload16(Asrc + kt * 32, sdst + kt * 16384);
    gload16(Bsrc + kt * 32, sdst + kt * 16384 + 8192);
    gload16(Asrc + (size_t)128 * DIM + kt * 32, sdst + kt * 16384 + 4096);
    gload16(Bsrc + (size_t)128 * DIM + kt * 32, sdst + kt * 16384 + 8192 + 4096);
  }
  asm volatile("s_waitcnt vmcnt(8)" ::: "memory");
  __builtin_amdgcn_s_barrier();

  for (int kt = 0; kt < NT - 3; ++kt) {
    ktile256<true>(kt, lds, Asrc, Bsrc, sdst, aoff, boff, acc);
    asm volatile("s_waitcnt vmcnt(8)" ::: "memory");   // kt+1 resident; kt+2,kt+3 in flight
    __builtin_amdgcn_s_barrier();
  }
  ktile256<false>(NT - 3, lds, Asrc, Bsrc, sdst, aoff, boff, acc);
  asm volatile("s_waitcnt vmcnt(4)" ::: "memory");
  __builtin_amdgcn_s_barrier();
  ktile256<false>(NT - 2, lds, Asrc, Bsrc, sdst, aoff, boff, acc);
  asm volatile("s_waitcnt vmcnt(0)" ::: "memory");
  __builtin_amdgcn_s_barrier();
  ktile256<false>(NT - 1, lds, Asrc, Bsrc, sdst, aoff, boff, acc);
}

// ---------------- QKV GEMM (256x256 ring): PURE row-major bf16 out, bias+scale folded ----------------
__global__ __launch_bounds__(512)
void gemm_qkv_kernel(const short* __restrict__ xb, const short* __restrict__ wqb,
                     const float* __restrict__ q_bias, const float* __restrict__ v_bias,
                     short* __restrict__ qkvb) {
  __shared__ __attribute__((aligned(16))) short lds[65536];   // 128 KB
  const int wg = xcd_swz(blockIdx.x, 50 * 9);
  const int tn = wg % 9, tm = wg / 9;   // tn fastest: A-tile L2-reuse
  f32x4 acc[8][4];
  gemm256_mainloop(xb, wqb, tm, tn, lds, acc);

  const int tid = threadIdx.x;
  const int w = tid >> 6, wm = w >> 2, wn = w & 3;
  const int l = tid & 63, lr = l & 15, lg = l >> 4;
  const int rbase = tm * 256 + wm * 128, cbase = tn * 256 + wn * 64;
#pragma unroll
  for (int n = 0; n < 4; ++n) {
    int c = cbase + n * 16 + lr;
    int part = (c < 768) ? 0 : ((c < 1536) ? 1 : 2);
    float bias = (part == 0) ? q_bias[c] : ((part == 2) ? v_bias[c - 1536] : 0.f);
    float scl = (part == 0) ? 0.125f : 1.f;
#pragma unroll
    for (int m = 0; m < 8; ++m) {
#pragma unroll
      for (int i = 0; i < 4; ++i) {
        int r = rbase + m * 16 + lg * 4 + i;   // always < M_PAD; pad rows never read
        qkvb[(size_t)r * QKVD + c] = f2bf((acc[m][n][i] + bias) * scl);
      }
    }
  }
}

// ---- 128x128 2-phase dbuf mainloop, 0-conflict XOR slot swizzle (round-4 proven) ----
__device__ inline void gemm_tile_mainloop128(const short* __restrict__ A, const short* __restrict__ Bw,
                                             int tm, int tn,
                                             short* As0, short* Bs0, short* As1, short* Bs1,
                                             f32x4 (&acc)[4][4]) {
  const int tid = threadIdx.x;
  const int l = tid & 63, lr = l & 15, lg = l >> 4;
  const int w = tid >> 6, wm = w >> 1, wn = w & 1;
  const int row = tid >> 2;
  const int c8 = (((tid & 3) ^ ((tid >> 3) & 3)) << 3);   // pre-swizzled source K-slot
  const int rs = (((lg ^ ((lr >> 1) & 3))) << 3);         // swizzled read K-slot
  const short* Ag = A + (size_t)(tm * 128 + row) * DIM + c8;
  const short* Bg = Bw + (size_t)(tn * 128 + row) * DIM + c8;
  const int dOff = tid * 8;
#pragma unroll
  for (int m = 0; m < 4; ++m)
#pragma unroll
    for (int n = 0; n < 4; ++n) { f32x4 z = {0.f, 0.f, 0.f, 0.f}; acc[m][n] = z; }

  gload16(Ag, As0 + dOff);
  gload16(Ag + (size_t)64 * DIM, As0 + 2048 + dOff);
  gload16(Bg, Bs0 + dOff);
  gload16(Bg + (size_t)64 * DIM, Bs0 + 2048 + dOff);
  __syncthreads();

  for (int kt = 0; kt < NT; ++kt) {
    short* Ac = (kt & 1) ? As1 : As0;
    short* Bc = (kt & 1) ? Bs1 : Bs0;
    short* An = (kt & 1) ? As0 : As1;
    short* Bn = (kt & 1) ? Bs0 : Bs1;
    if (kt < NT - 1) {
      gload16(Ag + (kt + 1) * 32, An + dOff);
      gload16(Ag + (size_t)64 * DIM + (kt + 1) * 32, An + 2048 + dOff);
      gload16(Bg + (kt + 1) * 32, Bn + dOff);
      gload16(Bg + (size_t)64 * DIM + (kt + 1) * 32, Bn + 2048 + dOff);
    }
    bf16x8 af[4], bfr[4];
#pragma unroll
    for (int m = 0; m < 4; ++m)
      af[m] = *(const bf16x8*)(Ac + (wm * 64 + m * 16 + lr) * 32 + rs);
#pragma unroll
    for (int n = 0; n < 4; ++n)
      bfr[n] = *(const bf16x8*)(Bc + (wn * 64 + n * 16 + lr) * 32 + rs);
#pragma unroll
    for (int m = 0; m < 4; ++m)
#pragma unroll
      for (int n = 0; n < 4; ++n)
        acc[m][n] = __builtin_amdgcn_mfma_f32_16x16x32_bf16(af[m], bfr[n], acc[m][n], 0, 0, 0);
    __syncthreads();
  }
}

// ---------------- attention: one block (8 waves) per (b,h), reads qkvb directly ----------------
__global__ __launch_bounds__(512, 1)
void attn_kernel(const short* __restrict__ qkvb, const float* __restrict__ rpbf,
                 short* __restrict__ aout) {
  __shared__ __attribute__((aligned(16))) short Klds[208 * 64];      // XOR-swizzled slots
  __shared__ __attribute__((aligned(16))) short Vlds[64 * NPS];      // V^T
  __shared__ __attribute__((aligned(16))) short Plds[8 * 16 * NPS];
  const int bh = blockIdx.x;
  const int b = bh / 12, h = bh - b * 12;
  const short* base = qkvb + (size_t)(b * 197) * QKVD;
  const short* Qg = base + h * 64;
  const short* Kg = base + 768 + h * 64;
  const short* Vg = base + 1536 + h * 64;
  const float* RP = rpbf + (size_t)h * NP * NP;
  const int tid = threadIdx.x;
  const int wave = tid >> 6, l = tid & 63, lr = l & 15, lg = l >> 4;

  // stage K swizzled (row-clamped: pad rows duplicate row 196, masked in softmax)
  for (int c = tid; c < 1664; c += 512) {
    int r = c >> 3, sp = c & 7;
    int rr = r < NTOK ? r : NTOK - 1;
    gload16(Kg + (size_t)rr * QKVD + ((sp ^ (r & 7)) << 3), Klds + c * 8);
  }
  // stage V transposed: read [t][d] coalesced, ds_write [d][t]
  for (int idx = tid; idx < 64 * NP; idx += 512) {
    int t = idx >> 6, d = idx & 63;
    int tt = t < NTOK ? t : NTOK - 1;
    Vlds[d * NPS + t] = Vg[(size_t)tt * QKVD + d];
  }
  __syncthreads();
  if (tid < 64) {
    for (int j = NP; j < NPS; ++j) Vlds[tid * NPS + j] = 0;  // pad cols of V^T
  }
  __syncthreads();

  short* Pw = Plds + wave * 16 * NPS;
  for (int s = wave; s < 13; s += 8) {
    const int row0 = s * 16;
    const int qrow = (row0 + lr < NTOK) ? (row0 + lr) : (NTOK - 1);
    bf16x8 qf0 = *(const bf16x8*)(Qg + (size_t)qrow * QKVD + lg * 8);
    bf16x8 qf1 = *(const bf16x8*)(Qg + (size_t)qrow * QKVD + 32 + lg * 8);
    f32x4 acc[13];
#pragma unroll
    for (int t = 0; t < 13; ++t) { f32x4 z = {0.f, 0.f, 0.f, 0.f}; acc[t] = z; }
    __builtin_amdgcn_s_setprio(1);
#pragma unroll
    for (int t = 0; t < 13; ++t) {
      int rk = t * 16 + lr;
      int sw = lr & 7;
      bf16x8 kf0 = *(const bf16x8*)(Klds + rk * 64 + ((lg ^ sw) << 3));
      bf16x8 kf1 = *(const bf16x8*)(Klds + rk * 64 + (((4 + lg) ^ sw) << 3));
      acc[t] = __builtin_amdgcn_mfma_f32_16x16x32_bf16(qf0, kf0, acc[t], 0, 0, 0);
      acc[t] = __builtin_amdgcn_mfma_f32_16x16x32_bf16(qf1, kf1, acc[t], 0, 0, 0);
    }
    __builtin_amdgcn_s_setprio(0);
    float sum4[4];
#pragma unroll
    for (int i = 0; i < 4; ++i) {
      const int row = row0 + lg * 4 + i;
      const float* rp = RP + (size_t)row * NP;
      float sv[13];
      float mx = -3e38f;
#pragma unroll
      for (int t = 0; t < 13; ++t) {
        int col = t * 16 + lr;
        float s_ = (col < NTOK) ? (acc[t][i] + rp[col]) : -3e38f;
        sv[t] = s_;
        mx = fmaxf(mx, s_);
      }
      mx = fmaxf(mx, __shfl_xor(mx, 1, 16));
      mx = fmaxf(mx, __shfl_xor(mx, 2, 16));
      mx = fmaxf(mx, __shfl_xor(mx, 4, 16));
      mx = fmaxf(mx, __shfl_xor(mx, 8, 16));
      float sm = 0.f;
#pragma unroll
      for (int t = 0; t < 13; ++t) {
        float p = __expf(sv[t] - mx);
        sm += p;
        Pw[(lg * 4 + i) * NPS + t * 16 + lr] = f2bf(p);
      }
      sm += __shfl_xor(sm, 1, 16);
      sm += __shfl_xor(sm, 2, 16);
      sm += __shfl_xor(sm, 4, 16);
      sm += __shfl_xor(sm, 8, 16);
      sum4[i] = sm;
      Pw[(lg * 4 + i) * NPS + 208 + lr] = 0;
    }
    f32x4 o[4];
#pragma unroll
    for (int dt = 0; dt < 4; ++dt) { f32x4 z = {0.f, 0.f, 0.f, 0.f}; o[dt] = z; }
    __builtin_amdgcn_s_setprio(1);
#pragma unroll
    for (int jb = 0; jb < 7; ++jb) {
      bf16x8 pf = *(const bf16x8*)(Pw + lr * NPS + jb * 32 + lg * 8);
#pragma unroll
      for (int dt = 0; dt < 4; ++dt) {
        bf16x8 vf = *(const bf16x8*)(Vlds + (dt * 16 + lr) * NPS + jb * 32 + lg * 8);
        o[dt] = __builtin_amdgcn_mfma_f32_16x16x32_bf16(pf, vf, o[dt], 0, 0, 0);
      }
    }
    __builtin_amdgcn_s_setprio(0);
#pragma unroll
    for (int i = 0; i < 4; ++i) {
      const int row = row0 + lg * 4 + i;
      if (row < NTOK) {
        float inv = 1.f / sum4[i];
        size_t base2 = (size_t)(b * 197 + row) * DIM + h * 64;
#pragma unroll
        for (int dt = 0; dt < 4; ++dt)
          aout[base2 + dt * 16 + lr] = f2bf(o[dt][i] * inv);
      }
    }
  }
}

// ---------------- proj GEMM (128x128): fp32 out + bias ----------------
__global__ void gemm_proj_kernel(const short* __restrict__ ab, const short* __restrict__ wpb,
                                 const float* __restrict__ proj_bias, float* __restrict__ out) {
  __shared__ __attribute__((aligned(16))) short As0[128 * 32];
  __shared__ __attribute__((aligned(16))) short Bs0[128 * 32];
  __shared__ __attribute__((aligned(16))) short As1[128 * 32];
  __shared__ __attribute__((aligned(16))) short Bs1[128 * 32];
  const int wg = xcd_swz(blockIdx.x, 99 * 6);
  const int tn = wg % 6, tm = wg / 6;
  f32x4 acc[4][4];
  gemm_tile_mainloop128(ab, wpb, tm, tn, As0, Bs0, As1, Bs1, acc);

  const int tid = threadIdx.x;
  const int w = tid >> 6, l = tid & 63, lr = l & 15, lg = l >> 4;
  const int wm = w >> 1, wn = w & 1;
  const int rbase = tm * 128 + wm * 64, cbase = tn * 128 + wn * 64;
#pragma unroll
  for (int n = 0; n < 4; ++n) {
    int c = cbase + n * 16 + lr;
    float pb = proj_bias[c];
#pragma unroll
    for (int m = 0; m < 4; ++m) {
#pragma unroll
      for (int i = 0; i < 4; ++i) {
        int r = rbase + m * 16 + lg * 4 + i;
        if (r < M_ROWS) out[(size_t)r * DIM + c] = acc[m][n][i] + pb;
      }
    }
  }
}

extern "C" void kernel_launch(void* const* d_in, const int* in_sizes, int n_in,
                              void* d_out, int out_size, void* d_ws, size_t ws_size,
                              hipStream_t stream) {
  const float* x         = (const float*)d_in[0];
  const float* wqkv      = (const float*)d_in[1];
  const float* q_bias    = (const float*)d_in[2];
  const float* v_bias    = (const float*)d_in[3];
  const float* table     = (const float*)d_in[4];
  const float* wproj     = (const float*)d_in[5];
  const float* proj_bias = (const float*)d_in[6];
  float* out = (float*)d_out;

  char* p = (char*)d_ws;
  short* xb    = (short*)p; p += (size_t)M_PAD * DIM * 2;       // 19.7 MB
  short* wqb   = (short*)p; p += (size_t)3 * DIM * DIM * 2;     //  3.5 MB
  short* wpb   = (short*)p; p += (size_t)DIM * DIM * 2;         //  1.2 MB
  short* qkvb  = (short*)p; p += (size_t)M_PAD * QKVD * 2;      // 59.0 MB
  float* rpbf  = (float*)p; p += (size_t)NHEADS * NP * NP * 4;  //  2.1 MB
  short* aout  = xb;  // reuse: xb is dead after gemm_qkv (pad rows stay zero)

  const int conv_tot = (M_ROWS * DIM + 3 * DIM * DIM + DIM * DIM + (M_PAD - M_ROWS) * DIM) / 4;
  convert_kernel<<<(conv_tot + 255) / 256, 256, 0, stream>>>(x, wqkv, wproj, xb, wqb, wpb);
  rpb_kernel<<<(NHEADS * NP * NP + 255) / 256, 256, 0, stream>>>(table, rpbf);
  gemm_qkv_kernel<<<50 * 9, 512, 0, stream>>>(xb, wqb, q_bias, v_bias, qkvb);
  attn_kernel<<<HEADS_TOT, 512, 0, stream>>>(qkvb, rpbf, aout);
  gemm_proj_kernel<<<99 * 6, 256, 0, stream>>>(aout, wpb, proj_bias, out);
}

// Round 9
// 148.360 us; speedup vs baseline: 1.3421x; 1.0084x over previous
//
#include <hip/hip_runtime.h>
#include <hip/hip_bf16.h>

#define DIM 768
#define QKVD 2304      // 3*DIM
#define NHEADS 12
#define NTOK 197
#define NP 208         // padded tokens (13*16)
#define NPS 232        // VT / P LDS row stride in shorts
#define M_ROWS 12608   // B*N
#define M_PAD 12800    // 100*128 = 50*256
#define HEADS_TOT 768  // B*H
#define NT 24          // K-tiles of 32 (768/32)

typedef __attribute__((ext_vector_type(8))) short bf16x8;
typedef __attribute__((ext_vector_type(4))) float f32x4;

__device__ inline short f2bf(float f) {
  union { __hip_bfloat16 h; short s; } u;
  u.h = __float2bfloat16(f);
  return u.s;
}

__device__ __forceinline__ void gload16(const short* g, short* l) {
  __builtin_amdgcn_global_load_lds((const __attribute__((address_space(1))) void*)g,
                                   (__attribute__((address_space(3))) void*)l, 16, 0, 0);
}

// bijective XCD-aware swizzle (m204)
__device__ __forceinline__ int xcd_swz(int orig, int nwg) {
  int q = nwg >> 3, r = nwg & 7;
  int x = orig & 7, p = orig >> 3;
  return (x < r ? x * (q + 1) : r * (q + 1) + (x - r) * q) + p;
}

// ---------------- convert fp32 -> bf16 (x, qkv_weight, proj_weight) + zero xb pad rows ----------------
__global__ void convert_kernel(const float* __restrict__ x, const float* __restrict__ wq,
                               const float* __restrict__ wp,
                               short* __restrict__ xb, short* __restrict__ wqb,
                               short* __restrict__ wpb) {
  int idx = blockIdx.x * 256 + threadIdx.x;
  const int n_x  = M_ROWS * DIM / 4;
  const int n_wq = 3 * DIM * DIM / 4;
  const int n_wp = DIM * DIM / 4;
  const int n_pad = (M_PAD - M_ROWS) * DIM / 4;
  if (idx >= n_x + n_wq + n_wp) {
    int k = idx - n_x - n_wq - n_wp;
    if (k < n_pad) {
      short4 z = {0, 0, 0, 0};
      *(short4*)(xb + (size_t)M_ROWS * DIM + (size_t)k * 4) = z;
    }
    return;
  }
  const float4* src; short* dst; int off;
  if (idx < n_x)             { src = (const float4*)x;  dst = xb;  off = idx; }
  else if (idx < n_x + n_wq) { src = (const float4*)wq; dst = wqb; off = idx - n_x; }
  else                       { src = (const float4*)wp; dst = wpb; off = idx - n_x - n_wq; }
  float4 v = src[off];
  short4 o;
  o.x = f2bf(v.x); o.y = f2bf(v.y); o.z = f2bf(v.z); o.w = f2bf(v.w);
  *(short4*)(dst + (size_t)off * 4) = o;
}

// ---------------- expand relative position bias to [12][208][208] fp32 ----------------
__global__ void rpb_kernel(const float* __restrict__ table, float* __restrict__ rpbf) {
  int idx = blockIdx.x * 256 + threadIdx.x;
  const int tot = NHEADS * NP * NP;
  if (idx >= tot) return;
  int h = idx / (NP * NP);
  int rem = idx - h * NP * NP;
  int i = rem / NP;
  int j = rem - i * NP;
  float v = 0.f;
  if (i < NTOK && j < NTOK) {
    int t;
    if (i == 0 && j == 0) t = 731;
    else if (i == 0)      t = 729;
    else if (j == 0)      t = 730;
    else {
      int p = i - 1, q = j - 1;
      int ri = p / 14, ci = p - ri * 14;
      int rj = q / 14, cj = q - rj * 14;
      t = (ri - rj + 13) * 27 + (ci - cj + 13);
    }
    v = table[t * NHEADS + h];
  }
  rpbf[idx] = v;
}

// ================= 256x256 pipelined GEMM: 4-deep ring + register-pipelined frags =================
// Per tile kt (steady): MFMA with preloaded afc/bfc while (a) staging tile kt+3 via
// global_load_lds, (b) ds_reading tile kt+1's fragments into afn/bfn. ONE barrier/tile.
// vmcnt(4) per tile keeps only kt's own 4 stages outstanding -> buf kt+2 resident one
// tile ahead of its fragment prefetch. Slot rotation (row>>1)&3 both sides: 0 conflicts.

__device__ __forceinline__ void tile_step(int kt, short* lds,
                                          const short* Asrc, const short* Bsrc, short* sdst,
                                          int aoff, int boff,
                                          bf16x8 (&afc)[8], bf16x8 (&bfc)[4],
                                          bf16x8 (&afn)[8], bf16x8 (&bfn)[4],
                                          f32x4 (&acc)[8][4]) {
  const bool stg = (kt < NT - 3);
  const bool pre = (kt < NT - 1);
  const short* nb = lds + ((kt + 1) & 3) * 16384;
  short* stgd = sdst + ((kt + 3) & 3) * 16384;
  const int kc = (kt + 3) * 32;
  // ---- phase A: stage 2, prefetch B + A-half0 of kt+1, 16 MFMA ----
  if (stg) { gload16(Asrc + kc, stgd); gload16(Bsrc + kc, stgd + 8192); }
  if (pre) {
#pragma unroll
    for (int n = 0; n < 4; ++n) bfn[n] = *(const bf16x8*)(nb + boff + n * 512);
#pragma unroll
    for (int j = 0; j < 4; ++j) afn[j] = *(const bf16x8*)(nb + aoff + j * 512);
  }
  __builtin_amdgcn_s_setprio(1);
#pragma unroll
  for (int j = 0; j < 4; ++j)
#pragma unroll
    for (int n = 0; n < 4; ++n)
      acc[j][n] = __builtin_amdgcn_mfma_f32_16x16x32_bf16(afc[j], bfc[n], acc[j][n], 0, 0, 0);
  __builtin_amdgcn_s_setprio(0);
  // ---- phase B: stage 2, prefetch A-half1 of kt+1, 16 MFMA ----
  if (stg) { gload16(Asrc + (size_t)128 * DIM + kc, stgd + 4096);
             gload16(Bsrc + (size_t)128 * DIM + kc, stgd + 8192 + 4096); }
  if (pre) {
#pragma unroll
    for (int j = 0; j < 4; ++j) afn[4 + j] = *(const bf16x8*)(nb + aoff + 2048 + j * 512);
  }
  __builtin_amdgcn_s_setprio(1);
#pragma unroll
  for (int j = 0; j < 4; ++j)
#pragma unroll
    for (int n = 0; n < 4; ++n)
      acc[4 + j][n] = __builtin_amdgcn_mfma_f32_16x16x32_bf16(afc[4 + j], bfc[n], acc[4 + j][n], 0, 0, 0);
  __builtin_amdgcn_s_setprio(0);
  // ---- end-of-tile: counted drain + single barrier ----
  if (kt < NT - 3)       { asm volatile("s_waitcnt vmcnt(4)" ::: "memory"); }
  else if (kt == NT - 3) { asm volatile("s_waitcnt vmcnt(0)" ::: "memory"); }
  __builtin_amdgcn_s_barrier();
}

__device__ __forceinline__ void gemm256_mainloop(const short* __restrict__ A,
                                                 const short* __restrict__ Bw,
                                                 int tm, int tn, short* lds, f32x4 (&acc)[8][4]) {
  const int tid = threadIdx.x;
  const int srow = tid >> 2;                         // staging row within half (0..127)
  const int sslot = ((tid & 3) - (tid >> 3)) & 3;    // pre-rotated source slot: (sp-(srow>>1))&3
  const int l = tid & 63, lr = l & 15, lg = l >> 4;
  const int w = tid >> 6, wm = w >> 2, wn = w & 3;
  const short* Asrc = A + (size_t)(tm * 256 + srow) * DIM + sslot * 8;
  const short* Bsrc = Bw + (size_t)(tn * 256 + srow) * DIM + sslot * 8;
  short* sdst = lds + tid * 8;                       // linear gload_lds dest
  const int slotR = (lg + (lr >> 1)) & 3;            // rotated read slot (per-lane constant)
  const int aoff = wm * 4096 + lr * 32 + slotR * 8;
  const int boff = 8192 + (wn >> 1) * 4096 + ((wn & 1) * 64 + lr) * 32 + slotR * 8;
#pragma unroll
  for (int m = 0; m < 8; ++m)
#pragma unroll
    for (int n = 0; n < 4; ++n) { f32x4 z = {0.f, 0.f, 0.f, 0.f}; acc[m][n] = z; }

  // prologue: stage K-tiles 0,1,2; drain tiles 0,1 (keep tile 2 in flight); preload tile-0 frags
#pragma unroll
  for (int kt = 0; kt < 3; ++kt) {
    gload16(Asrc + kt * 32, sdst + kt * 16384);
    gload16(Bsrc + kt * 32, sdst + kt * 16384 + 8192);
    gload16(Asrc + (size_t)128 * DIM + kt * 32, sdst + kt * 16384 + 4096);
    gload16(Bsrc + (size_t)128 * DIM + kt * 32, sdst + kt * 16384 + 8192 + 4096);
  }
  asm volatile("s_waitcnt vmcnt(4)" ::: "memory");
  __builtin_amdgcn_s_barrier();

  bf16x8 afA[8], bfA[4], afB[8], bfB[4];
#pragma unroll
  for (int n = 0; n < 4; ++n) bfA[n] = *(const bf16x8*)(lds + boff + n * 512);
#pragma unroll
  for (int j = 0; j < 4; ++j) afA[j] = *(const bf16x8*)(lds + aoff + j * 512);
#pragma unroll
  for (int j = 0; j < 4; ++j) afA[4 + j] = *(const bf16x8*)(lds + aoff + 2048 + j * 512);

  for (int kt = 0; kt < NT; kt += 2) {
    tile_step(kt,     lds, Asrc, Bsrc, sdst, aoff, boff, afA, bfA, afB, bfB, acc);
    tile_step(kt + 1, lds, Asrc, Bsrc, sdst, aoff, boff, afB, bfB, afA, bfA, acc);
  }
}

// ---------------- QKV GEMM (256x256 ring): PURE row-major bf16 out, bias+scale folded ----------------
__global__ __launch_bounds__(512, 2)
void gemm_qkv_kernel(const short* __restrict__ xb, const short* __restrict__ wqb,
                     const float* __restrict__ q_bias, const float* __restrict__ v_bias,
                     short* __restrict__ qkvb) {
  __shared__ __attribute__((aligned(16))) short lds[65536];   // 128 KB
  const int wg = xcd_swz(blockIdx.x, 50 * 9);
  const int tn = wg % 9, tm = wg / 9;   // tn fastest: A-tile L2-reuse
  f32x4 acc[8][4];
  gemm256_mainloop(xb, wqb, tm, tn, lds, acc);

  const int tid = threadIdx.x;
  const int w = tid >> 6, wm = w >> 2, wn = w & 3;
  const int l = tid & 63, lr = l & 15, lg = l >> 4;
  const int rbase = tm * 256 + wm * 128, cbase = tn * 256 + wn * 64;
#pragma unroll
  for (int n = 0; n < 4; ++n) {
    int c = cbase + n * 16 + lr;
    int part = (c < 768) ? 0 : ((c < 1536) ? 1 : 2);
    float bias = (part == 0) ? q_bias[c] : ((part == 2) ? v_bias[c - 1536] : 0.f);
    float scl = (part == 0) ? 0.125f : 1.f;
#pragma unroll
    for (int m = 0; m < 8; ++m) {
#pragma unroll
      for (int i = 0; i < 4; ++i) {
        int r = rbase + m * 16 + lg * 4 + i;   // always < M_PAD; pad rows never read
        qkvb[(size_t)r * QKVD + c] = f2bf((acc[m][n][i] + bias) * scl);
      }
    }
  }
}

// ---- 128x128 2-phase dbuf mainloop, 0-conflict XOR slot swizzle (round-4 proven) ----
__device__ inline void gemm_tile_mainloop128(const short* __restrict__ A, const short* __restrict__ Bw,
                                             int tm, int tn,
                                             short* As0, short* Bs0, short* As1, short* Bs1,
                                             f32x4 (&acc)[4][4]) {
  const int tid = threadIdx.x;
  const int l = tid & 63, lr = l & 15, lg = l >> 4;
  const int w = tid >> 6, wm = w >> 1, wn = w & 1;
  const int row = tid >> 2;
  const int c8 = (((tid & 3) ^ ((tid >> 3) & 3)) << 3);   // pre-swizzled source K-slot
  const int rs = (((lg ^ ((lr >> 1) & 3))) << 3);         // swizzled read K-slot
  const short* Ag = A + (size_t)(tm * 128 + row) * DIM + c8;
  const short* Bg = Bw + (size_t)(tn * 128 + row) * DIM + c8;
  const int dOff = tid * 8;
#pragma unroll
  for (int m = 0; m < 4; ++m)
#pragma unroll
    for (int n = 0; n < 4; ++n) { f32x4 z = {0.f, 0.f, 0.f, 0.f}; acc[m][n] = z; }

  gload16(Ag, As0 + dOff);
  gload16(Ag + (size_t)64 * DIM, As0 + 2048 + dOff);
  gload16(Bg, Bs0 + dOff);
  gload16(Bg + (size_t)64 * DIM, Bs0 + 2048 + dOff);
  __syncthreads();

  for (int kt = 0; kt < NT; ++kt) {
    short* Ac = (kt & 1) ? As1 : As0;
    short* Bc = (kt & 1) ? Bs1 : Bs0;
    short* An = (kt & 1) ? As0 : As1;
    short* Bn = (kt & 1) ? Bs0 : Bs1;
    if (kt < NT - 1) {
      gload16(Ag + (kt + 1) * 32, An + dOff);
      gload16(Ag + (size_t)64 * DIM + (kt + 1) * 32, An + 2048 + dOff);
      gload16(Bg + (kt + 1) * 32, Bn + dOff);
      gload16(Bg + (size_t)64 * DIM + (kt + 1) * 32, Bn + 2048 + dOff);
    }
    bf16x8 af[4], bfr[4];
#pragma unroll
    for (int m = 0; m < 4; ++m)
      af[m] = *(const bf16x8*)(Ac + (wm * 64 + m * 16 + lr) * 32 + rs);
#pragma unroll
    for (int n = 0; n < 4; ++n)
      bfr[n] = *(const bf16x8*)(Bc + (wn * 64 + n * 16 + lr) * 32 + rs);
#pragma unroll
    for (int m = 0; m < 4; ++m)
#pragma unroll
      for (int n = 0; n < 4; ++n)
        acc[m][n] = __builtin_amdgcn_mfma_f32_16x16x32_bf16(af[m], bfr[n], acc[m][n], 0, 0, 0);
    __syncthreads();
  }
}

// ---------------- attention: one block (8 waves) per (b,h), reads qkvb directly ----------------
__global__ __launch_bounds__(512, 1)
void attn_kernel(const short* __restrict__ qkvb, const float* __restrict__ rpbf,
                 short* __restrict__ aout) {
  __shared__ __attribute__((aligned(16))) short Klds[208 * 64];      // XOR-swizzled slots
  __shared__ __attribute__((aligned(16))) short Vlds[64 * NPS];      // V^T
  __shared__ __attribute__((aligned(16))) short Plds[8 * 16 * NPS];
  const int bh = blockIdx.x;
  const int b = bh / 12, h = bh - b * 12;
  const short* base = qkvb + (size_t)(b * 197) * QKVD;
  const short* Qg = base + h * 64;
  const short* Kg = base + 768 + h * 64;
  const short* Vg = base + 1536 + h * 64;
  const float* RP = rpbf + (size_t)h * NP * NP;
  const int tid = threadIdx.x;
  const int wave = tid >> 6, l = tid & 63, lr = l & 15, lg = l >> 4;

  // stage K swizzled (row-clamped: pad rows duplicate row 196, masked in softmax)
  for (int c = tid; c < 1664; c += 512) {
    int r = c >> 3, sp = c & 7;
    int rr = r < NTOK ? r : NTOK - 1;
    gload16(Kg + (size_t)rr * QKVD + ((sp ^ (r & 7)) << 3), Klds + c * 8);
  }
  // stage V transposed: read [t][d] coalesced, ds_write [d][t]
  for (int idx = tid; idx < 64 * NP; idx += 512) {
    int t = idx >> 6, d = idx & 63;
    int tt = t < NTOK ? t : NTOK - 1;
    Vlds[d * NPS + t] = Vg[(size_t)tt * QKVD + d];
  }
  __syncthreads();
  if (tid < 64) {
    for (int j = NP; j < NPS; ++j) Vlds[tid * NPS + j] = 0;  // pad cols of V^T
  }
  __syncthreads();

  short* Pw = Plds + wave * 16 * NPS;
  for (int s = wave; s < 13; s += 8) {
    const int row0 = s * 16;
    const int qrow = (row0 + lr < NTOK) ? (row0 + lr) : (NTOK - 1);
    bf16x8 qf0 = *(const bf16x8*)(Qg + (size_t)qrow * QKVD + lg * 8);
    bf16x8 qf1 = *(const bf16x8*)(Qg + (size_t)qrow * QKVD + 32 + lg * 8);
    f32x4 acc[13];
#pragma unroll
    for (int t = 0; t < 13; ++t) { f32x4 z = {0.f, 0.f, 0.f, 0.f}; acc[t] = z; }
    __builtin_amdgcn_s_setprio(1);
#pragma unroll
    for (int t = 0; t < 13; ++t) {
      int rk = t * 16 + lr;
      int sw = lr & 7;
      bf16x8 kf0 = *(const bf16x8*)(Klds + rk * 64 + ((lg ^ sw) << 3));
      bf16x8 kf1 = *(const bf16x8*)(Klds + rk * 64 + (((4 + lg) ^ sw) << 3));
      acc[t] = __builtin_amdgcn_mfma_f32_16x16x32_bf16(qf0, kf0, acc[t], 0, 0, 0);
      acc[t] = __builtin_amdgcn_mfma_f32_16x16x32_bf16(qf1, kf1, acc[t], 0, 0, 0);
    }
    __builtin_amdgcn_s_setprio(0);
    float sum4[4];
#pragma unroll
    for (int i = 0; i < 4; ++i) {
      const int row = row0 + lg * 4 + i;
      const float* rp = RP + (size_t)row * NP;
      float sv[13];
      float mx = -3e38f;
#pragma unroll
      for (int t = 0; t < 13; ++t) {
        int col = t * 16 + lr;
        float s_ = (col < NTOK) ? (acc[t][i] + rp[col]) : -3e38f;
        sv[t] = s_;
        mx = fmaxf(mx, s_);
      }
      mx = fmaxf(mx, __shfl_xor(mx, 1, 16));
      mx = fmaxf(mx, __shfl_xor(mx, 2, 16));
      mx = fmaxf(mx, __shfl_xor(mx, 4, 16));
      mx = fmaxf(mx, __shfl_xor(mx, 8, 16));
      float sm = 0.f;
#pragma unroll
      for (int t = 0; t < 13; ++t) {
        float p = __expf(sv[t] - mx);
        sm += p;
        Pw[(lg * 4 + i) * NPS + t * 16 + lr] = f2bf(p);
      }
      sm += __shfl_xor(sm, 1, 16);
      sm += __shfl_xor(sm, 2, 16);
      sm += __shfl_xor(sm, 4, 16);
      sm += __shfl_xor(sm, 8, 16);
      sum4[i] = sm;
      Pw[(lg * 4 + i) * NPS + 208 + lr] = 0;
    }
    f32x4 o[4];
#pragma unroll
    for (int dt = 0; dt < 4; ++dt) { f32x4 z = {0.f, 0.f, 0.f, 0.f}; o[dt] = z; }
    __builtin_amdgcn_s_setprio(1);
#pragma unroll
    for (int jb = 0; jb < 7; ++jb) {
      bf16x8 pf = *(const bf16x8*)(Pw + lr * NPS + jb * 32 + lg * 8);
#pragma unroll
      for (int dt = 0; dt < 4; ++dt) {
        bf16x8 vf = *(const bf16x8*)(Vlds + (dt * 16 + lr) * NPS + jb * 32 + lg * 8);
        o[dt] = __builtin_amdgcn_mfma_f32_16x16x32_bf16(pf, vf, o[dt], 0, 0, 0);
      }
    }
    __builtin_amdgcn_s_setprio(0);
#pragma unroll
    for (int i = 0; i < 4; ++i) {
      const int row = row0 + lg * 4 + i;
      if (row < NTOK) {
        float inv = 1.f / sum4[i];
        size_t base2 = (size_t)(b * 197 + row) * DIM + h * 64;
#pragma unroll
        for (int dt = 0; dt < 4; ++dt)
          aout[base2 + dt * 16 + lr] = f2bf(o[dt][i] * inv);
      }
    }
  }
}

// ---------------- proj GEMM (128x128): fp32 out + bias ----------------
__global__ void gemm_proj_kernel(const short* __restrict__ ab, const short* __restrict__ wpb,
                                 const float* __restrict__ proj_bias, float* __restrict__ out) {
  __shared__ __attribute__((aligned(16))) short As0[128 * 32];
  __shared__ __attribute__((aligned(16))) short Bs0[128 * 32];
  __shared__ __attribute__((aligned(16))) short As1[128 * 32];
  __shared__ __attribute__((aligned(16))) short Bs1[128 * 32];
  const int wg = xcd_swz(blockIdx.x, 99 * 6);
  const int tn = wg % 6, tm = wg / 6;
  f32x4 acc[4][4];
  gemm_tile_mainloop128(ab, wpb, tm, tn, As0, Bs0, As1, Bs1, acc);

  const int tid = threadIdx.x;
  const int w = tid >> 6, l = tid & 63, lr = l & 15, lg = l >> 4;
  const int wm = w >> 1, wn = w & 1;
  const int rbase = tm * 128 + wm * 64, cbase = tn * 128 + wn * 64;
#pragma unroll
  for (int n = 0; n < 4; ++n) {
    int c = cbase + n * 16 + lr;
    float pb = proj_bias[c];
#pragma unroll
    for (int m = 0; m < 4; ++m) {
#pragma unroll
      for (int i = 0; i < 4; ++i) {
        int r = rbase + m * 16 + lg * 4 + i;
        if (r < M_ROWS) out[(size_t)r * DIM + c] = acc[m][n][i] + pb;
      }
    }
  }
}

extern "C" void kernel_launch(void* const* d_in, const int* in_sizes, int n_in,
                              void* d_out, int out_size, void* d_ws, size_t ws_size,
                              hipStream_t stream) {
  const float* x         = (const float*)d_in[0];
  const float* wqkv      = (const float*)d_in[1];
  const float* q_bias    = (const float*)d_in[2];
  const float* v_bias    = (const float*)d_in[3];
  const float* table     = (const float*)d_in[4];
  const float* wproj     = (const float*)d_in[5];
  const float* proj_bias = (const float*)d_in[6];
  float* out = (float*)d_out;

  char* p = (char*)d_ws;
  short* xb    = (short*)p; p += (size_t)M_PAD * DIM * 2;       // 19.7 MB
  short* wqb   = (short*)p; p += (size_t)3 * DIM * DIM * 2;     //  3.5 MB
  short* wpb   = (short*)p; p += (size_t)DIM * DIM * 2;         //  1.2 MB
  short* qkvb  = (short*)p; p += (size_t)M_PAD * QKVD * 2;      // 59.0 MB
  float* rpbf  = (float*)p; p += (size_t)NHEADS * NP * NP * 4;  //  2.1 MB
  short* aout  = xb;  // reuse: xb is dead after gemm_qkv (pad rows stay zero)

  const int conv_tot = (M_ROWS * DIM + 3 * DIM * DIM + DIM * DIM + (M_PAD - M_ROWS) * DIM) / 4;
  convert_kernel<<<(conv_tot + 255) / 256, 256, 0, stream>>>(x, wqkv, wproj, xb, wqb, wpb);
  rpb_kernel<<<(NHEADS * NP * NP + 255) / 256, 256, 0, stream>>>(table, rpbf);
  gemm_qkv_kernel<<<50 * 9, 512, 0, stream>>>(xb, wqb, q_bias, v_bias, qkvb);
  attn_kernel<<<HEADS_TOT, 512, 0, stream>>>(qkvb, rpbf, aout);
  gemm_proj_kernel<<<99 * 6, 256, 0, stream>>>(aout, wpb, proj_bias, out);
}

// Round 10
// 141.603 us; speedup vs baseline: 1.4062x; 1.0477x over previous
//
#include <hip/hip_runtime.h>
#include <hip/hip_bf16.h>

#define DIM 768
#define QKVD 2304      // 3*DIM
#define NHEADS 12
#define NTOK 197
#define NP 208         // padded tokens (13*16)
#define NPS 232        // VT / P LDS row stride in shorts
#define M_ROWS 12608   // B*N
#define M_PAD 12800    // 100*128 = 50*256
#define HEADS_TOT 768  // B*H
#define NT 24          // K-tiles of 32 (768/32)

typedef __attribute__((ext_vector_type(8))) short bf16x8;
typedef __attribute__((ext_vector_type(4))) float f32x4;

__device__ inline short f2bf(float f) {
  union { __hip_bfloat16 h; short s; } u;
  u.h = __float2bfloat16(f);
  return u.s;
}

__device__ __forceinline__ void gload16(const short* g, short* l) {
  __builtin_amdgcn_global_load_lds((const __attribute__((address_space(1))) void*)g,
                                   (__attribute__((address_space(3))) void*)l, 16, 0, 0);
}

// bijective XCD-aware swizzle (m204)
__device__ __forceinline__ int xcd_swz(int orig, int nwg) {
  int q = nwg >> 3, r = nwg & 7;
  int x = orig & 7, p = orig >> 3;
  return (x < r ? x * (q + 1) : r * (q + 1) + (x - r) * q) + p;
}

// ---------------- prep: fp32->bf16 converts + xb pad zero + rpb expansion (fused) ----------------
__global__ void prep_kernel(const float* __restrict__ x, const float* __restrict__ wq,
                            const float* __restrict__ wp, const float* __restrict__ table,
                            short* __restrict__ xb, short* __restrict__ wqb,
                            short* __restrict__ wpb, float* __restrict__ rpbf) {
  int idx = blockIdx.x * 256 + threadIdx.x;
  const int n_x  = M_ROWS * DIM / 4;
  const int n_wq = 3 * DIM * DIM / 4;
  const int n_wp = DIM * DIM / 4;
  const int n_pad = (M_PAD - M_ROWS) * DIM / 4;
  const int conv_tot = n_x + n_wq + n_wp + n_pad;
  if (idx < conv_tot) {
    if (idx >= n_x + n_wq + n_wp) {
      int k = idx - n_x - n_wq - n_wp;
      short4 z = {0, 0, 0, 0};
      *(short4*)(xb + (size_t)M_ROWS * DIM + (size_t)k * 4) = z;
      return;
    }
    const float4* src; short* dst; int off;
    if (idx < n_x)             { src = (const float4*)x;  dst = xb;  off = idx; }
    else if (idx < n_x + n_wq) { src = (const float4*)wq; dst = wqb; off = idx - n_x; }
    else                       { src = (const float4*)wp; dst = wpb; off = idx - n_x - n_wq; }
    float4 v = src[off];
    short4 o;
    o.x = f2bf(v.x); o.y = f2bf(v.y); o.z = f2bf(v.z); o.w = f2bf(v.w);
    *(short4*)(dst + (size_t)off * 4) = o;
    return;
  }
  int ridx = idx - conv_tot;
  if (ridx >= NHEADS * NP * NP) return;
  int h = ridx / (NP * NP);
  int rem = ridx - h * NP * NP;
  int i = rem / NP;
  int j = rem - i * NP;
  float v = 0.f;
  if (i < NTOK && j < NTOK) {
    int t;
    if (i == 0 && j == 0) t = 731;
    else if (i == 0)      t = 729;
    else if (j == 0)      t = 730;
    else {
      int p = i - 1, q = j - 1;
      int ri = p / 14, ci = p - ri * 14;
      int rj = q / 14, cj = q - rj * 14;
      t = (ri - rj + 13) * 27 + (ci - cj + 13);
    }
    v = table[t * NHEADS + h];
  }
  rpbf[ridx] = v;
}

// ================= 256x256 ring GEMM (BK=32, 4-deep, counted vmcnt, reg-pipelined frags) =================
__device__ __forceinline__ void tile_step(int kt, short* lds,
                                          const short* Asrc, const short* Bsrc, short* sdst,
                                          int aoff, int boff,
                                          bf16x8 (&afc)[8], bf16x8 (&bfc)[4],
                                          bf16x8 (&afn)[8], bf16x8 (&bfn)[4],
                                          f32x4 (&acc)[8][4]) {
  const bool stg = (kt < NT - 3);
  const bool pre = (kt < NT - 1);
  const short* nb = lds + ((kt + 1) & 3) * 16384;
  short* stgd = sdst + ((kt + 3) & 3) * 16384;
  const int kc = (kt + 3) * 32;
  // ---- phase A ----
  if (stg) { gload16(Asrc + kc, stgd); gload16(Bsrc + kc, stgd + 8192); }
  if (pre) {
#pragma unroll
    for (int n = 0; n < 4; ++n) bfn[n] = *(const bf16x8*)(nb + boff + n * 512);
#pragma unroll
    for (int j = 0; j < 4; ++j) afn[j] = *(const bf16x8*)(nb + aoff + j * 512);
  }
  __builtin_amdgcn_s_setprio(1);
#pragma unroll
  for (int j = 0; j < 4; ++j)
#pragma unroll
    for (int n = 0; n < 4; ++n)
      acc[j][n] = __builtin_amdgcn_mfma_f32_16x16x32_bf16(afc[j], bfc[n], acc[j][n], 0, 0, 0);
  __builtin_amdgcn_s_setprio(0);
  // ---- phase B ----
  if (stg) { gload16(Asrc + (size_t)128 * DIM + kc, stgd + 4096);
             gload16(Bsrc + (size_t)128 * DIM + kc, stgd + 8192 + 4096); }
  if (pre) {
#pragma unroll
    for (int j = 0; j < 4; ++j) afn[4 + j] = *(const bf16x8*)(nb + aoff + 2048 + j * 512);
  }
  __builtin_amdgcn_s_setprio(1);
#pragma unroll
  for (int j = 0; j < 4; ++j)
#pragma unroll
    for (int n = 0; n < 4; ++n)
      acc[4 + j][n] = __builtin_amdgcn_mfma_f32_16x16x32_bf16(afc[4 + j], bfc[n], acc[4 + j][n], 0, 0, 0);
  __builtin_amdgcn_s_setprio(0);
  if (kt < NT - 3)       { asm volatile("s_waitcnt vmcnt(4)" ::: "memory"); }
  else if (kt == NT - 3) { asm volatile("s_waitcnt vmcnt(0)" ::: "memory"); }
  __builtin_amdgcn_s_barrier();
}

__device__ __forceinline__ void gemm256_mainloop(const short* __restrict__ A,
                                                 const short* __restrict__ Bw,
                                                 int tm, int tn, short* lds, f32x4 (&acc)[8][4]) {
  const int tid = threadIdx.x;
  const int srow = tid >> 2;
  const int sslot = ((tid & 3) - (tid >> 3)) & 3;
  const int l = tid & 63, lr = l & 15, lg = l >> 4;
  const int w = tid >> 6, wm = w >> 2, wn = w & 3;
  const short* Asrc = A + (size_t)(tm * 256 + srow) * DIM + sslot * 8;
  const short* Bsrc = Bw + (size_t)(tn * 256 + srow) * DIM + sslot * 8;
  short* sdst = lds + tid * 8;
  const int slotR = (lg + (lr >> 1)) & 3;
  const int aoff = wm * 4096 + lr * 32 + slotR * 8;
  const int boff = 8192 + (wn >> 1) * 4096 + ((wn & 1) * 64 + lr) * 32 + slotR * 8;
#pragma unroll
  for (int m = 0; m < 8; ++m)
#pragma unroll
    for (int n = 0; n < 4; ++n) { f32x4 z = {0.f, 0.f, 0.f, 0.f}; acc[m][n] = z; }

#pragma unroll
  for (int kt = 0; kt < 3; ++kt) {
    gload16(Asrc + kt * 32, sdst + kt * 16384);
    gload16(Bsrc + kt * 32, sdst + kt * 16384 + 8192);
    gload16(Asrc + (size_t)128 * DIM + kt * 32, sdst + kt * 16384 + 4096);
    gload16(Bsrc + (size_t)128 * DIM + kt * 32, sdst + kt * 16384 + 8192 + 4096);
  }
  asm volatile("s_waitcnt vmcnt(4)" ::: "memory");
  __builtin_amdgcn_s_barrier();

  bf16x8 afA[8], bfA[4], afB[8], bfB[4];
#pragma unroll
  for (int n = 0; n < 4; ++n) bfA[n] = *(const bf16x8*)(lds + boff + n * 512);
#pragma unroll
  for (int j = 0; j < 4; ++j) afA[j] = *(const bf16x8*)(lds + aoff + j * 512);
#pragma unroll
  for (int j = 0; j < 4; ++j) afA[4 + j] = *(const bf16x8*)(lds + aoff + 2048 + j * 512);

  for (int kt = 0; kt < NT; kt += 2) {
    tile_step(kt,     lds, Asrc, Bsrc, sdst, aoff, boff, afA, bfA, afB, bfB, acc);
    tile_step(kt + 1, lds, Asrc, Bsrc, sdst, aoff, boff, afB, bfB, afA, bfA, acc);
  }
}

// ---------------- QKV GEMM: ring mainloop + LDS-staged coalesced epilogue ----------------
__global__ __launch_bounds__(512, 2)
void gemm_qkv_kernel(const short* __restrict__ xb, const short* __restrict__ wqb,
                     const float* __restrict__ q_bias, const float* __restrict__ v_bias,
                     short* __restrict__ qkvb) {
  __shared__ __attribute__((aligned(16))) short lds[65536];   // 128 KB
  const int wg = xcd_swz(blockIdx.x, 50 * 9);
  const int tn = wg % 9, tm = wg / 9;
  f32x4 acc[8][4];
  gemm256_mainloop(xb, wqb, tm, tn, lds, acc);

  const int tid = threadIdx.x;
  const int w = tid >> 6, wm = w >> 2, wn = w & 3;
  const int l = tid & 63, lr = l & 15, lg = l >> 4;
  const int cbase = tn * 256 + wn * 64;
  // epilogue via LDS: per 128-row half, dump bf16 at stride 264 (<=2-way banks),
  // then store full 512B row segments (4 full 128B lines per bf16x8 store).
  for (int half = 0; half < 2; ++half) {
    if (wm == half) {
#pragma unroll
      for (int n = 0; n < 4; ++n) {
        int c = cbase + n * 16 + lr;
        int part = (c < 768) ? 0 : ((c < 1536) ? 1 : 2);
        float bias = (part == 0) ? q_bias[c] : ((part == 2) ? v_bias[c - 1536] : 0.f);
        float scl = (part == 0) ? 0.125f : 1.f;
#pragma unroll
        for (int m = 0; m < 8; ++m)
#pragma unroll
          for (int i = 0; i < 4; ++i)
            lds[(m * 16 + lg * 4 + i) * 264 + wn * 64 + n * 16 + lr] =
                f2bf((acc[m][n][i] + bias) * scl);
      }
    }
    __syncthreads();
#pragma unroll
    for (int p = 0; p < 8; ++p) {
      int chunk = tid + p * 512;
      int row = chunk >> 5, ch = chunk & 31;
      bf16x8 v = *(const bf16x8*)(lds + row * 264 + ch * 8);
      *(bf16x8*)(qkvb + (size_t)(tm * 256 + half * 128 + row) * QKVD + tn * 256 + ch * 8) = v;
    }
    __syncthreads();
  }
}

// ================= 128x128 ring GEMM for proj (4-deep, 256 threads, 64KB -> 2 blocks/CU) =================
__device__ __forceinline__ void tile_step128(int kt, short* lds,
                                             const short* Asrc, const short* Bsrc, short* sdst,
                                             int aoff, int boff,
                                             bf16x8 (&afc)[4], bf16x8 (&bfc)[4],
                                             bf16x8 (&afn)[4], bf16x8 (&bfn)[4],
                                             f32x4 (&acc)[4][4]) {
  const bool stg = (kt < NT - 3);
  const bool pre = (kt < NT - 1);
  const short* nb = lds + ((kt + 1) & 3) * 8192;
  short* stgd = sdst + ((kt + 3) & 3) * 8192;
  const int kc = (kt + 3) * 32;
  // ---- phase A ----
  if (stg) { gload16(Asrc + kc, stgd); gload16(Bsrc + kc, stgd + 4096); }
  if (pre) {
#pragma unroll
    for (int n = 0; n < 4; ++n) bfn[n] = *(const bf16x8*)(nb + boff + n * 512);
#pragma unroll
    for (int j = 0; j < 2; ++j) afn[j] = *(const bf16x8*)(nb + aoff + j * 512);
  }
  __builtin_amdgcn_s_setprio(1);
#pragma unroll
  for (int j = 0; j < 2; ++j)
#pragma unroll
    for (int n = 0; n < 4; ++n)
      acc[j][n] = __builtin_amdgcn_mfma_f32_16x16x32_bf16(afc[j], bfc[n], acc[j][n], 0, 0, 0);
  __builtin_amdgcn_s_setprio(0);
  // ---- phase B ----
  if (stg) { gload16(Asrc + (size_t)64 * DIM + kc, stgd + 2048);
             gload16(Bsrc + (size_t)64 * DIM + kc, stgd + 4096 + 2048); }
  if (pre) {
#pragma unroll
    for (int j = 2; j < 4; ++j) afn[j] = *(const bf16x8*)(nb + aoff + j * 512);
  }
  __builtin_amdgcn_s_setprio(1);
#pragma unroll
  for (int j = 2; j < 4; ++j)
#pragma unroll
    for (int n = 0; n < 4; ++n)
      acc[j][n] = __builtin_amdgcn_mfma_f32_16x16x32_bf16(afc[j], bfc[n], acc[j][n], 0, 0, 0);
  __builtin_amdgcn_s_setprio(0);
  if (kt < NT - 3)       { asm volatile("s_waitcnt vmcnt(4)" ::: "memory"); }
  else if (kt == NT - 3) { asm volatile("s_waitcnt vmcnt(0)" ::: "memory"); }
  __builtin_amdgcn_s_barrier();
}

__global__ __launch_bounds__(256, 2)
void gemm_proj_kernel(const short* __restrict__ ab, const short* __restrict__ wpb,
                      const float* __restrict__ proj_bias, float* __restrict__ out) {
  __shared__ __attribute__((aligned(16))) short lds[32768];   // 64 KB -> 2 blocks/CU
  const int wg = xcd_swz(blockIdx.x, 99 * 6);
  const int tn = wg % 6, tm = wg / 6;
  const int tid = threadIdx.x;
  const int srow = tid >> 2;                        // 0..63
  const int sslot = ((tid & 3) - (tid >> 3)) & 3;
  const int l = tid & 63, lr = l & 15, lg = l >> 4;
  const int w = tid >> 6, wm = w >> 1, wn = w & 1;
  const short* Asrc = ab + (size_t)(tm * 128 + srow) * DIM + sslot * 8;
  const short* Bsrc = wpb + (size_t)(tn * 128 + srow) * DIM + sslot * 8;
  short* sdst = lds + tid * 8;
  const int slotR = (lg + (lr >> 1)) & 3;
  const int aoff = wm * 2048 + lr * 32 + slotR * 8;
  const int boff = 4096 + wn * 2048 + lr * 32 + slotR * 8;
  f32x4 acc[4][4];
#pragma unroll
  for (int m = 0; m < 4; ++m)
#pragma unroll
    for (int n = 0; n < 4; ++n) { f32x4 z = {0.f, 0.f, 0.f, 0.f}; acc[m][n] = z; }

#pragma unroll
  for (int kt = 0; kt < 3; ++kt) {
    gload16(Asrc + kt * 32, sdst + kt * 8192);
    gload16(Bsrc + kt * 32, sdst + kt * 8192 + 4096);
    gload16(Asrc + (size_t)64 * DIM + kt * 32, sdst + kt * 8192 + 2048);
    gload16(Bsrc + (size_t)64 * DIM + kt * 32, sdst + kt * 8192 + 4096 + 2048);
  }
  asm volatile("s_waitcnt vmcnt(4)" ::: "memory");
  __builtin_amdgcn_s_barrier();

  bf16x8 afA[4], bfA[4], afB[4], bfB[4];
#pragma unroll
  for (int n = 0; n < 4; ++n) bfA[n] = *(const bf16x8*)(lds + boff + n * 512);
#pragma unroll
  for (int j = 0; j < 4; ++j) afA[j] = *(const bf16x8*)(lds + aoff + j * 512);

  for (int kt = 0; kt < NT; kt += 2) {
    tile_step128(kt,     lds, Asrc, Bsrc, sdst, aoff, boff, afA, bfA, afB, bfB, acc);
    tile_step128(kt + 1, lds, Asrc, Bsrc, sdst, aoff, boff, afB, bfB, afA, bfA, acc);
  }

  // epilogue via LDS (f32, stride 132 floats, 64-row halves), coalesced float4 stores
  float* ldsF = (float*)lds;
  for (int half = 0; half < 2; ++half) {
    if (wm == half) {
#pragma unroll
      for (int n = 0; n < 4; ++n) {
        int c = tn * 128 + wn * 64 + n * 16 + lr;
        float pb = proj_bias[c];
#pragma unroll
        for (int m = 0; m < 4; ++m)
#pragma unroll
          for (int i = 0; i < 4; ++i)
            ldsF[(m * 16 + lg * 4 + i) * 132 + wn * 64 + n * 16 + lr] = acc[m][n][i] + pb;
      }
    }
    __syncthreads();
#pragma unroll
    for (int p = 0; p < 8; ++p) {
      int chunk = tid + p * 256;
      int row = chunk >> 5, ch = chunk & 31;
      int r = tm * 128 + half * 64 + row;
      if (r < M_ROWS) {
        f32x4 v = *(const f32x4*)(ldsF + row * 132 + ch * 4);
        *(f32x4*)(out + (size_t)r * DIM + tn * 128 + ch * 4) = v;
      }
    }
    __syncthreads();
  }
}

// ---------------- attention: one block (8 waves) per (b,h), reads qkvb directly ----------------
__global__ __launch_bounds__(512, 1)
void attn_kernel(const short* __restrict__ qkvb, const float* __restrict__ rpbf,
                 short* __restrict__ aout) {
  __shared__ __attribute__((aligned(16))) short Klds[208 * 64];
  __shared__ __attribute__((aligned(16))) short Vlds[64 * NPS];
  __shared__ __attribute__((aligned(16))) short Plds[8 * 16 * NPS];
  const int bh = blockIdx.x;
  const int b = bh / 12, h = bh - b * 12;
  const short* base = qkvb + (size_t)(b * 197) * QKVD;
  const short* Qg = base + h * 64;
  const short* Kg = base + 768 + h * 64;
  const short* Vg = base + 1536 + h * 64;
  const float* RP = rpbf + (size_t)h * NP * NP;
  const int tid = threadIdx.x;
  const int wave = tid >> 6, l = tid & 63, lr = l & 15, lg = l >> 4;

  for (int c = tid; c < 1664; c += 512) {
    int r = c >> 3, sp = c & 7;
    int rr = r < NTOK ? r : NTOK - 1;
    gload16(Kg + (size_t)rr * QKVD + ((sp ^ (r & 7)) << 3), Klds + c * 8);
  }
  for (int idx = tid; idx < 64 * NP; idx += 512) {
    int t = idx >> 6, d = idx & 63;
    int tt = t < NTOK ? t : NTOK - 1;
    Vlds[d * NPS + t] = Vg[(size_t)tt * QKVD + d];
  }
  __syncthreads();
  if (tid < 64) {
    for (int j = NP; j < NPS; ++j) Vlds[tid * NPS + j] = 0;
  }
  __syncthreads();

  short* Pw = Plds + wave * 16 * NPS;
  for (int s = wave; s < 13; s += 8) {
    const int row0 = s * 16;
    const int qrow = (row0 + lr < NTOK) ? (row0 + lr) : (NTOK - 1);
    bf16x8 qf0 = *(const bf16x8*)(Qg + (size_t)qrow * QKVD + lg * 8);
    bf16x8 qf1 = *(const bf16x8*)(Qg + (size_t)qrow * QKVD + 32 + lg * 8);
    f32x4 acc[13];
#pragma unroll
    for (int t = 0; t < 13; ++t) { f32x4 z = {0.f, 0.f, 0.f, 0.f}; acc[t] = z; }
    __builtin_amdgcn_s_setprio(1);
#pragma unroll
    for (int t = 0; t < 13; ++t) {
      int rk = t * 16 + lr;
      int sw = lr & 7;
      bf16x8 kf0 = *(const bf16x8*)(Klds + rk * 64 + ((lg ^ sw) << 3));
      bf16x8 kf1 = *(const bf16x8*)(Klds + rk * 64 + (((4 + lg) ^ sw) << 3));
      acc[t] = __builtin_amdgcn_mfma_f32_16x16x32_bf16(qf0, kf0, acc[t], 0, 0, 0);
      acc[t] = __builtin_amdgcn_mfma_f32_16x16x32_bf16(qf1, kf1, acc[t], 0, 0, 0);
    }
    __builtin_amdgcn_s_setprio(0);
    float sum4[4];
#pragma unroll
    for (int i = 0; i < 4; ++i) {
      const int row = row0 + lg * 4 + i;
      const float* rp = RP + (size_t)row * NP;
      float sv[13];
      float mx = -3e38f;
#pragma unroll
      for (int t = 0; t < 13; ++t) {
        int col = t * 16 + lr;
        float s_ = (col < NTOK) ? (acc[t][i] + rp[col]) : -3e38f;
        sv[t] = s_;
        mx = fmaxf(mx, s_);
      }
      mx = fmaxf(mx, __shfl_xor(mx, 1, 16));
      mx = fmaxf(mx, __shfl_xor(mx, 2, 16));
      mx = fmaxf(mx, __shfl_xor(mx, 4, 16));
      mx = fmaxf(mx, __shfl_xor(mx, 8, 16));
      float sm = 0.f;
#pragma unroll
      for (int t = 0; t < 13; ++t) {
        float p = __expf(sv[t] - mx);
        sm += p;
        Pw[(lg * 4 + i) * NPS + t * 16 + lr] = f2bf(p);
      }
      sm += __shfl_xor(sm, 1, 16);
      sm += __shfl_xor(sm, 2, 16);
      sm += __shfl_xor(sm, 4, 16);
      sm += __shfl_xor(sm, 8, 16);
      sum4[i] = sm;
      Pw[(lg * 4 + i) * NPS + 208 + lr] = 0;
    }
    f32x4 o[4];
#pragma unroll
    for (int dt = 0; dt < 4; ++dt) { f32x4 z = {0.f, 0.f, 0.f, 0.f}; o[dt] = z; }
    __builtin_amdgcn_s_setprio(1);
#pragma unroll
    for (int jb = 0; jb < 7; ++jb) {
      bf16x8 pf = *(const bf16x8*)(Pw + lr * NPS + jb * 32 + lg * 8);
#pragma unroll
      for (int dt = 0; dt < 4; ++dt) {
        bf16x8 vf = *(const bf16x8*)(Vlds + (dt * 16 + lr) * NPS + jb * 32 + lg * 8);
        o[dt] = __builtin_amdgcn_mfma_f32_16x16x32_bf16(pf, vf, o[dt], 0, 0, 0);
      }
    }
    __builtin_amdgcn_s_setprio(0);
#pragma unroll
    for (int i = 0; i < 4; ++i) {
      const int row = row0 + lg * 4 + i;
      if (row < NTOK) {
        float inv = 1.f / sum4[i];
        size_t base2 = (size_t)(b * 197 + row) * DIM + h * 64;
#pragma unroll
        for (int dt = 0; dt < 4; ++dt)
          aout[base2 + dt * 16 + lr] = f2bf(o[dt][i] * inv);
      }
    }
  }
}

extern "C" void kernel_launch(void* const* d_in, const int* in_sizes, int n_in,
                              void* d_out, int out_size, void* d_ws, size_t ws_size,
                              hipStream_t stream) {
  const float* x         = (const float*)d_in[0];
  const float* wqkv      = (const float*)d_in[1];
  const float* q_bias    = (const float*)d_in[2];
  const float* v_bias    = (const float*)d_in[3];
  const float* table     = (const float*)d_in[4];
  const float* wproj     = (const float*)d_in[5];
  const float* proj_bias = (const float*)d_in[6];
  float* out = (float*)d_out;

  char* p = (char*)d_ws;
  short* xb    = (short*)p; p += (size_t)M_PAD * DIM * 2;
  short* wqb   = (short*)p; p += (size_t)3 * DIM * DIM * 2;
  short* wpb   = (short*)p; p += (size_t)DIM * DIM * 2;
  short* qkvb  = (short*)p; p += (size_t)M_PAD * QKVD * 2;
  float* rpbf  = (float*)p; p += (size_t)NHEADS * NP * NP * 4;
  short* aout  = xb;  // reuse: xb is dead after gemm_qkv (pad rows stay zero)

  const int conv_tot = (M_ROWS * DIM + 3 * DIM * DIM + DIM * DIM + (M_PAD - M_ROWS) * DIM) / 4;
  const int prep_tot = conv_tot + NHEADS * NP * NP;
  prep_kernel<<<(prep_tot + 255) / 256, 256, 0, stream>>>(x, wqkv, wproj, table, xb, wqb, wpb, rpbf);
  gemm_qkv_kernel<<<50 * 9, 512, 0, stream>>>(xb, wqb, q_bias, v_bias, qkvb);
  attn_kernel<<<HEADS_TOT, 512, 0, stream>>>(qkvb, rpbf, aout);
  gemm_proj_kernel<<<99 * 6, 256, 0, stream>>>(aout, wpb, proj_bias, out);
}